// Round 4
// baseline (889.994 us; speedup 1.0000x reference)
//
#include <hip/hip_runtime.h>
#include <math.h>
#include <cstdint>

// ---------------- problem constants ----------------
#define NN     131072     // nodes
#define DDIM   128        // hidden dim
#define NHEAD  4
#define HDIM   32
#define NTYPE  3
#define NEDGE  262144     // edges per type (2^18)
#define NGRAPH 512
#define EPSV   1e-6f
#define SLOPEV 0.2f

typedef unsigned short bfraw;
typedef __attribute__((ext_vector_type(8))) short bf16x8;
typedef __attribute__((ext_vector_type(4))) float f32x4;

// ---------------- helpers ----------------
__device__ __forceinline__ float lrelu(float x){ return x >= 0.f ? x : SLOPEV*x; }
__device__ __forceinline__ float gelu_f(float x){ return 0.5f*x*(1.f+erff(x*0.70710678118654752f)); }
__device__ __forceinline__ bfraw f2bf(float f){
  unsigned int u = __float_as_uint(f);
  u += 0x7fffu + ((u >> 16) & 1u);          // RNE
  return (bfraw)(u >> 16);
}
__device__ __forceinline__ float4 ld_bf4(const bfraw* p){
  uint2 u = *reinterpret_cast<const uint2*>(p);
  float4 r;
  r.x = __uint_as_float(u.x << 16); r.y = __uint_as_float(u.x & 0xffff0000u);
  r.z = __uint_as_float(u.y << 16); r.w = __uint_as_float(u.y & 0xffff0000u);
  return r;
}
__device__ __forceinline__ bf16x8 pack_bf8(const float* p){
  float4 u = *reinterpret_cast<const float4*>(p);
  float4 v = *reinterpret_cast<const float4*>(p+4);
  bf16x8 r;
  r[0]=(short)f2bf(u.x); r[1]=(short)f2bf(u.y); r[2]=(short)f2bf(u.z); r[3]=(short)f2bf(u.w);
  r[4]=(short)f2bf(v.x); r[5]=(short)f2bf(v.y); r[6]=(short)f2bf(v.z); r[7]=(short)f2bf(v.w);
  return r;
}

// ---------------- generic fill ----------------
__global__ void fill_k(float* __restrict__ p, float v, int n){
  int i = blockIdx.x*blockDim.x + threadIdx.x;
  int stride = gridDim.x*blockDim.x;
  for (; i < n; i += stride) p[i] = v;
}

// ---------------- CSR build (dst-sorted, per edge type) ----------------
__global__ void hist_k(const int* __restrict__ ei, int* __restrict__ deg){
  int idx = blockIdx.x*256 + threadIdx.x;          // < 3E
  int t = idx >> 18, e = idx & (NEDGE-1);
  int d = ei[(long)t*2*NEDGE + NEDGE + e];
  atomicAdd(&deg[t*NN + d], 1);
}

__global__ void scan_a_k(const int* __restrict__ deg, int* __restrict__ rp,
                         int* __restrict__ csum){
  __shared__ int sh[256];
  int t = blockIdx.y, chunk = blockIdx.x, tid = threadIdx.x;
  const int* dp = deg + (long)t*NN + chunk*2048 + tid*8;
  int v[8]; int s = 0;
  #pragma unroll
  for (int i=0;i<8;i++){ v[i] = dp[i]; s += v[i]; }
  sh[tid] = s; __syncthreads();
  for (int off=1; off<256; off<<=1){
    int x = (tid>=off) ? sh[tid-off] : 0;
    __syncthreads();
    sh[tid] += x;
    __syncthreads();
  }
  int run = sh[tid] - s;                            // exclusive prefix
  int* op = rp + (long)t*(NN+1) + chunk*2048 + tid*8;
  #pragma unroll
  for (int i=0;i<8;i++){ op[i] = run; run += v[i]; }
  if (tid == 255) csum[t*64 + chunk] = sh[255];
}

__global__ void scan_b_k(int* __restrict__ csum){
  __shared__ int sh[64];
  int t = blockIdx.x, tid = threadIdx.x;
  int s = csum[t*64 + tid];
  sh[tid] = s; __syncthreads();
  for (int off=1; off<64; off<<=1){
    int x = (tid>=off) ? sh[tid-off] : 0;
    __syncthreads();
    sh[tid] += x;
    __syncthreads();
  }
  csum[t*64 + tid] = sh[tid] - s;                   // exclusive
}

__global__ void scan_c_k(int* __restrict__ rp, const int* __restrict__ csum){
  int t = blockIdx.y, chunk = blockIdx.x, tid = threadIdx.x;
  int add = csum[t*64 + chunk];
  int* op = rp + (long)t*(NN+1) + chunk*2048 + tid*8;
  #pragma unroll
  for (int i=0;i<8;i++) op[i] += add;
  if (chunk == 63 && tid == 255) rp[(long)t*(NN+1) + NN] = NEDGE;
}

__global__ void scatter_k(const int* __restrict__ ei, const int* __restrict__ rp,
                          int* __restrict__ cnt, int* __restrict__ srcs){
  int idx = blockIdx.x*256 + threadIdx.x;          // < 3E
  int t = idx >> 18, e = idx & (NEDGE-1);
  int s = ei[(long)t*2*NEDGE + e];
  int d = ei[(long)t*2*NEDGE + NEDGE + e];
  int pos = rp[(long)t*(NN+1) + d] + atomicAdd(&cnt[t*NN + d], 1);
  srcs[(long)t*NEDGE + pos] = s;
}

// ---------------- weight swizzle: f32 [128,128] -> bf16 b-frag layout ----------------
__global__ void wswz_k(const float* g0a, const float* g0b, const float* g0c,
                       const float* g1a, const float* g1b, const float* g1c,
                       const float* qw,
                       const float* wk, const float* wv,   // [3][128][128] each
                       const float* aw, const float* injw,
                       bfraw* __restrict__ Wall)
{
  int y = blockIdx.y;
  const float* src;
  switch(y){
    case 0: src = g0a; break;  case 1: src = g0b; break;  case 2: src = g0c; break;
    case 3: src = g1a; break;  case 4: src = g1b; break;  case 5: src = g1c; break;
    case 6: src = qw; break;
    case 7: case 8: case 9: src = wk + (long)(y-7)*16384; break;
    case 10: case 11: case 12: src = wv + (long)(y-10)*16384; break;
    case 13: src = aw; break;
    default: src = injw; break;
  }
  int i = blockIdx.x*256 + threadIdx.x;            // < 16384
  int j = i & 7, lane = (i>>3) & 63, kc = (i>>9) & 3, nt = i >> 11;
  int k = kc*32 + ((lane>>4)<<3) + j;
  int n = nt*16 + (lane & 15);
  Wall[(long)y*16384 + i] = f2bf(src[k*DDIM + n]);
}

// ---------------- GAT score projection, directly in swizzled b-frag layout ----------
__global__ void gatproj_k(const float* __restrict__ w, const float* __restrict__ asrc,
                          const float* __restrict__ adst, bfraw* __restrict__ out)
{
  int i = blockIdx.x*256 + threadIdx.x;            // < 4096
  int j = i & 7, lane = (i>>3) & 63, kc = (i>>9) & 3, nt = i >> 11;   // nt 0..1
  int k = kc*32 + ((lane>>4)<<3) + j;
  int n = nt*16 + (lane & 15);
  float s = 0.f;
  if (n < 24){
    int t = n >> 3, sd = (n >> 2) & 1, hh = n & 3;
    const float* a  = (sd ? adst : asrc) + ((long)t*NHEAD + hh)*HDIM;
    const float* wr = w + ((long)t*DDIM + k)*DDIM + hh*HDIM;
    #pragma unroll 8
    for (int dd=0; dd<HDIM; dd++) s += wr[dd]*a[dd];
  }
  out[i] = f2bf(s);
}

// ---------------- MFMA GEMM building blocks -----------------------------------------
__device__ __forceinline__ void load_afrags_bf16(const bfraw* __restrict__ A,
    long blockRow, int tid, bf16x8 a0[4], bf16x8 a1[4])
{
  const int w = tid >> 6, lane = tid & 63;
  const long rowA = blockRow + w*32 + (lane & 15);
  const bfraw* A0 = A + rowA*DDIM + ((lane>>4)<<3);
  #pragma unroll
  for (int kc=0;kc<4;kc++){
    a0[kc] = *reinterpret_cast<const bf16x8*>(A0 + kc*32);
    a1[kc] = *reinterpret_cast<const bf16x8*>(A0 + 16*DDIM + kc*32);
  }
}

__device__ __forceinline__ void load_afrags_f32(const float* __restrict__ A,
    long blockRow, int tid, bf16x8 a0[4], bf16x8 a1[4])
{
  const int w = tid >> 6, lane = tid & 63;
  const long rowA = blockRow + w*32 + (lane & 15);
  const float* A0 = A + rowA*DDIM + ((lane>>4)<<3);
  #pragma unroll
  for (int kc=0;kc<4;kc++){
    a0[kc] = pack_bf8(A0 + kc*32);
    a1[kc] = pack_bf8(A0 + 16*DDIM + kc*32);
  }
}

__device__ __forceinline__ void mfma_128(const bfraw* Wl, int lane,
    bf16x8 a0[4], bf16x8 a1[4], f32x4 acc0[8], f32x4 acc1[8])
{
  const f32x4 zz = {0.f,0.f,0.f,0.f};
  #pragma unroll
  for (int nt=0;nt<8;nt++){ acc0[nt]=zz; acc1[nt]=zz; }
  #pragma unroll
  for (int nt=0;nt<8;nt++){
    #pragma unroll
    for (int kc=0;kc<4;kc++){
      bf16x8 b = *reinterpret_cast<const bf16x8*>(Wl + ((nt*4+kc)*64 + lane)*8);
      acc0[nt] = __builtin_amdgcn_mfma_f32_16x16x32_bf16(a0[kc], b, acc0[nt], 0, 0, 0);
      acc1[nt] = __builtin_amdgcn_mfma_f32_16x16x32_bf16(a1[kc], b, acc1[nt], 0, 0, 0);
    }
  }
}

__device__ __forceinline__ void gemm_store_bf16(f32x4 acc0[8], f32x4 acc1[8],
    const float* bias, bfraw* __restrict__ Cb, long blockRow, int tid)
{
  const int w = tid>>6, lane = tid&63, q = lane>>4;
  #pragma unroll
  for (int g=0; g<2; g++){
    #pragma unroll
    for (int nt=0;nt<8;nt++){
      int col = nt*16 + (lane & 15);
      float bv = bias ? bias[col] : 0.f;
      #pragma unroll
      for (int r=0;r<4;r++){
        long row = blockRow + w*32 + g*16 + q*4 + r;
        float v = (g ? acc1[nt][r] : acc0[nt][r]) + bv;
        Cb[row*DDIM + col] = f2bf(v);
      }
    }
  }
}

// ---- up to 4 GEMMs sharing one A-read (+ optional 24-col score GEMM tail) ----------
__global__ __launch_bounds__(256) void gemm3_k(
    const bfraw* __restrict__ Ab, const float* __restrict__ Af,
    const bfraw* __restrict__ W0, const bfraw* __restrict__ W1,
    const bfraw* __restrict__ W2,
    const float* __restrict__ b0, const float* __restrict__ b1,
    const float* __restrict__ b2,
    bfraw* __restrict__ O0, bfraw* __restrict__ O1, bfraw* __restrict__ O2,
    const bfraw* __restrict__ Psw, float* __restrict__ SS,
    const bfraw* __restrict__ W3, const float* __restrict__ b3,
    bfraw* __restrict__ O3)
{
  __shared__ bfraw Wl[16384];
  const int tid = threadIdx.x;
  const long blockRow = (long)blockIdx.x * 128;
  const int w = tid >> 6, lane = tid & 63;
  bf16x8 a0[4], a1[4];
  if (Af) load_afrags_f32(Af, blockRow, tid, a0, a1);
  else    load_afrags_bf16(Ab, blockRow, tid, a0, a1);
  const bfraw* Ws[3] = {W0, W1, W2};
  const float* bs[3] = {b0, b1, b2};
  bfraw* Os[3] = {O0, O1, O2};
  #pragma unroll
  for (int t=0;t<3;t++){
    __syncthreads();                                 // prev readers done
    #pragma unroll
    for (int i=0;i<8;i++)
      *reinterpret_cast<uint4*>(Wl + (i*256+tid)*8) =
          *reinterpret_cast<const uint4*>(Ws[t] + (i*256+tid)*8);
    __syncthreads();
    f32x4 acc0[8], acc1[8];
    mfma_128(Wl, lane, a0, a1, acc0, acc1);
    gemm_store_bf16(acc0, acc1, bs[t], Os[t], blockRow, tid);
  }
  if (W3){
    __syncthreads();
    #pragma unroll
    for (int i=0;i<8;i++)
      *reinterpret_cast<uint4*>(Wl + (i*256+tid)*8) =
          *reinterpret_cast<const uint4*>(W3 + (i*256+tid)*8);
    __syncthreads();
    f32x4 acc0[8], acc1[8];
    mfma_128(Wl, lane, a0, a1, acc0, acc1);
    gemm_store_bf16(acc0, acc1, b3, O3, blockRow, tid);
  }
  if (Psw){
    __syncthreads();
    #pragma unroll
    for (int i=0;i<2;i++)
      *reinterpret_cast<uint4*>(Wl + (i*256+tid)*8) =
          *reinterpret_cast<const uint4*>(Psw + (i*256+tid)*8);
    __syncthreads();
    const f32x4 zz = {0.f,0.f,0.f,0.f};
    f32x4 acc0[2], acc1[2];
    #pragma unroll
    for (int nt=0;nt<2;nt++){ acc0[nt]=zz; acc1[nt]=zz; }
    #pragma unroll
    for (int nt=0;nt<2;nt++){
      #pragma unroll
      for (int kc=0;kc<4;kc++){
        bf16x8 b = *reinterpret_cast<const bf16x8*>(Wl + ((nt*4+kc)*64 + lane)*8);
        acc0[nt] = __builtin_amdgcn_mfma_f32_16x16x32_bf16(a0[kc], b, acc0[nt], 0, 0, 0);
        acc1[nt] = __builtin_amdgcn_mfma_f32_16x16x32_bf16(a1[kc], b, acc1[nt], 0, 0, 0);
      }
    }
    const int q = lane >> 4;
    #pragma unroll
    for (int g=0; g<2; g++){
      #pragma unroll
      for (int nt=0;nt<2;nt++){
        int col = nt*16 + (lane & 15);
        if (col < 24){
          int tt = col >> 3, c = col & 7;           // SS layout [T][NN][8]
          #pragma unroll
          for (int r=0;r<4;r++){
            long row = blockRow + w*32 + g*16 + q*4 + r;
            SS[(((long)tt*NN + row)<<3) + c] = (g ? acc1[nt][r] : acc0[nt][r]);
          }
        }
      }
    }
  }
}

// ---- fused: GEMM(attn@aw) + res3 + GEMM(x_emb@injw) + FiLM -> out ------------------
__global__ __launch_bounds__(256) void gemm_r3film_k(
    const bfraw* __restrict__ Aattn, const bfraw* __restrict__ Waw,
    const float* __restrict__ ab, const float* __restrict__ X,
    const float* __restrict__ norm, const float* __restrict__ skip,
    const float* __restrict__ xemb, const bfraw* __restrict__ Winj,
    const float* __restrict__ injb, const float* __restrict__ gbt,
    float* __restrict__ out)
{
  __shared__ bfraw Wl[16384];
  const int tid = threadIdx.x;
  const long blockRow = (long)blockIdx.x * 128;
  // GEMM1: attn-out @ aw
  #pragma unroll
  for (int i=0;i<8;i++)
    *reinterpret_cast<uint4*>(Wl + (i*256+tid)*8) =
        *reinterpret_cast<const uint4*>(Waw + (i*256+tid)*8);
  __syncthreads();
  bf16x8 a0[4], a1[4];
  load_afrags_bf16(Aattn, blockRow, tid, a0, a1);
  f32x4 accA0[8], accA1[8];
  mfma_128(Wl, tid & 63, a0, a1, accA0, accA1);
  __syncthreads();
  // GEMM2: x_emb(f32) @ injw
  #pragma unroll
  for (int i=0;i<8;i++)
    *reinterpret_cast<uint4*>(Wl + (i*256+tid)*8) =
        *reinterpret_cast<const uint4*>(Winj + (i*256+tid)*8);
  __syncthreads();
  load_afrags_f32(xemb, blockRow, tid, a0, a1);
  f32x4 accB0[8], accB1[8];
  mfma_128(Wl, tid & 63, a0, a1, accB0, accB1);
  // epilogue
  const int w = tid>>6, lane = tid&63, q = lane>>4;
  const float gsk = 1.f/(1.f + __expf(-skip[0]));
  #pragma unroll
  for (int g=0; g<2; g++){
    #pragma unroll
    for (int r=0;r<4;r++){
      long row = blockRow + w*32 + g*16 + q*4 + r;
      float vv[8], xx[8];
      float sq = 0.f;
      #pragma unroll
      for (int nt=0;nt<8;nt++){
        int col = nt*16 + (lane & 15);
        float oA = (g ? accA1[nt][r] : accA0[nt][r]) + ab[col];
        float xo = X[row*DDIM + col];
        float v  = gsk*oA + (1.f-gsk)*xo;
        vv[nt] = v; xx[nt] = xo; sq += v*v;
      }
      sq += __shfl_xor(sq, 1, 64);
      sq += __shfl_xor(sq, 2, 64);
      sq += __shfl_xor(sq, 4, 64);
      sq += __shfl_xor(sq, 8, 64);
      float rr = rsqrtf(sq*(1.f/DDIM) + EPSV);
      long gi = row >> 8;                             // 256 nodes per graph
      #pragma unroll
      for (int nt=0;nt<8;nt++){
        int col = nt*16 + (lane & 15);
        float x3 = lrelu(xx[nt] + norm[col]*vv[nt]*rr);
        float vB = (g ? accB1[nt][r] : accB0[nt][r]) + injb[col] + x3;
        out[row*DDIM + col] = (1.f + gbt[gi*256 + col])*vB + gbt[gi*256 + 128 + col];
      }
    }
  }
}

// ---------------- fused GAT: cross-type interleaved (6 gather chains) ---------------
// SS layout: [T][NN][8], cols 0..3 = ss per head, 4..7 = ds per head.
// Per-type softmax (separate denominators), outputs summed, then bias+RMS+residual.
__global__ __launch_bounds__(256) void gat_fused_k(
    const int* __restrict__ rp, const int* __restrict__ srcs,
    const bfraw* __restrict__ H0, const bfraw* __restrict__ H1,
    const bfraw* __restrict__ H2, const float* __restrict__ SS,
    const float* __restrict__ gatb, const float* __restrict__ xold,
    const float* __restrict__ norm, float* __restrict__ X, bfraw* __restrict__ Xb)
{
  int node = blockIdx.x*8 + (threadIdx.x >> 5);
  int l = threadIdx.x & 31;
  int hd = l >> 3;
  const float* S0 = SS;
  const float* S1 = SS + (long)NN*8;
  const float* S2 = SS + (long)2*NN*8;
  // hoisted per-type self state (independent loads issue together)
  float d0 = S0[(long)node*8 + 4 + hd];
  float d1 = S1[(long)node*8 + 4 + hd];
  float d2 = S2[(long)node*8 + 4 + hd];
  float z0 = S0[(long)node*8 + hd];
  float z1 = S1[(long)node*8 + hd];
  float z2 = S2[(long)node*8 + hd];
  float4 h0 = ld_bf4(H0 + (long)node*DDIM + l*4);
  float4 h1 = ld_bf4(H1 + (long)node*DDIM + l*4);
  float4 h2 = ld_bf4(H2 + (long)node*DDIM + l*4);
  float w0 = __expf(lrelu(z0 + d0));
  float w1 = __expf(lrelu(z1 + d1));
  float w2 = __expf(lrelu(z2 + d2));
  float l0 = w0, l1 = w1, l2 = w2;
  float4 A0 = make_float4(w0*h0.x, w0*h0.y, w0*h0.z, w0*h0.w);
  float4 A1 = make_float4(w1*h1.x, w1*h1.y, w1*h1.z, w1*h1.w);
  float4 A2 = make_float4(w2*h2.x, w2*h2.y, w2*h2.z, w2*h2.w);
  int p0 = rp[node],            e0 = rp[node+1];
  int p1 = rp[(NN+1)+node],     e1 = rp[(NN+1)+node+1];
  int p2 = rp[2*(NN+1)+node],   e2 = rp[2*(NN+1)+node+1];
  const int* sp0 = srcs;
  const int* sp1 = srcs + NEDGE;
  const int* sp2 = srcs + (long)2*NEDGE;
  while (p0 < e0 || p1 < e1 || p2 < e2){
    bool b0a = p0 < e0, b0b = p0+1 < e0;
    bool b1a = p1 < e1, b1b = p1+1 < e1;
    bool b2a = p2 < e2, b2b = p2+1 < e2;
    int s0a = b0a ? sp0[p0]   : node;
    int s0b = b0b ? sp0[p0+1] : node;
    int s1a = b1a ? sp1[p1]   : node;
    int s1b = b1b ? sp1[p1+1] : node;
    int s2a = b2a ? sp2[p2]   : node;
    int s2b = b2b ? sp2[p2+1] : node;
    float v0a = S0[(long)s0a*8 + hd], v0b = S0[(long)s0b*8 + hd];
    float v1a = S1[(long)s1a*8 + hd], v1b = S1[(long)s1b*8 + hd];
    float v2a = S2[(long)s2a*8 + hd], v2b = S2[(long)s2b*8 + hd];
    float4 g0a = ld_bf4(H0 + (long)s0a*DDIM + l*4);
    float4 g0b = ld_bf4(H0 + (long)s0b*DDIM + l*4);
    float4 g1a = ld_bf4(H1 + (long)s1a*DDIM + l*4);
    float4 g1b = ld_bf4(H1 + (long)s1b*DDIM + l*4);
    float4 g2a = ld_bf4(H2 + (long)s2a*DDIM + l*4);
    float4 g2b = ld_bf4(H2 + (long)s2b*DDIM + l*4);
    float e0a = b0a ? __expf(lrelu(v0a + d0)) : 0.f;
    float e0b = b0b ? __expf(lrelu(v0b + d0)) : 0.f;
    float e1a = b1a ? __expf(lrelu(v1a + d1)) : 0.f;
    float e1b = b1b ? __expf(lrelu(v1b + d1)) : 0.f;
    float e2a = b2a ? __expf(lrelu(v2a + d2)) : 0.f;
    float e2b = b2b ? __expf(lrelu(v2b + d2)) : 0.f;
    l0 += e0a + e0b; l1 += e1a + e1b; l2 += e2a + e2b;
    A0.x += e0a*g0a.x + e0b*g0b.x; A0.y += e0a*g0a.y + e0b*g0b.y;
    A0.z += e0a*g0a.z + e0b*g0b.z; A0.w += e0a*g0a.w + e0b*g0b.w;
    A1.x += e1a*g1a.x + e1b*g1b.x; A1.y += e1a*g1a.y + e1b*g1b.y;
    A1.z += e1a*g1a.z + e1b*g1b.z; A1.w += e1a*g1a.w + e1b*g1b.w;
    A2.x += e2a*g2a.x + e2b*g2b.x; A2.y += e2a*g2a.y + e2b*g2b.y;
    A2.z += e2a*g2a.z + e2b*g2b.z; A2.w += e2a*g2a.w + e2b*g2b.w;
    p0 += (b0a?1:0) + (b0b?1:0);
    p1 += (b1a?1:0) + (b1b?1:0);
    p2 += (b2a?1:0) + (b2b?1:0);
  }
  float i0 = 1.f/l0, i1 = 1.f/l1, i2 = 1.f/l2;
  float tx = A0.x*i0 + A1.x*i1 + A2.x*i2;
  float ty = A0.y*i0 + A1.y*i1 + A2.y*i2;
  float tz = A0.z*i0 + A1.z*i1 + A2.z*i2;
  float tw = A0.w*i0 + A1.w*i1 + A2.w*i2;
  int f = l*4;
  tx += gatb[f]   + gatb[DDIM+f]   + gatb[2*DDIM+f];
  ty += gatb[f+1] + gatb[DDIM+f+1] + gatb[2*DDIM+f+1];
  tz += gatb[f+2] + gatb[DDIM+f+2] + gatb[2*DDIM+f+2];
  tw += gatb[f+3] + gatb[DDIM+f+3] + gatb[2*DDIM+f+3];
  float sq = tx*tx + ty*ty + tz*tz + tw*tw;
  sq += __shfl_xor(sq, 1, 64);
  sq += __shfl_xor(sq, 2, 64);
  sq += __shfl_xor(sq, 4, 64);
  sq += __shfl_xor(sq, 8, 64);
  sq += __shfl_xor(sq, 16, 64);
  float r = rsqrtf(sq*(1.f/DDIM) + EPSV);
  float4 x4 = *reinterpret_cast<const float4*>(xold + (long)node*DDIM + f);
  float4 o;
  o.x = lrelu(x4.x + norm[f]  *tx*r);
  o.y = lrelu(x4.y + norm[f+1]*ty*r);
  o.z = lrelu(x4.z + norm[f+2]*tz*r);
  o.w = lrelu(x4.w + norm[f+3]*tw*r);
  *reinterpret_cast<float4*>(X + (long)node*DDIM + f) = o;
  unsigned int lo = ((unsigned int)f2bf(o.y) << 16) | f2bf(o.x);
  unsigned int hi = ((unsigned int)f2bf(o.w) << 16) | f2bf(o.z);
  *reinterpret_cast<uint2*>(Xb + (long)node*DDIM + f) = make_uint2(lo, hi);
}

// ---------------- HGT: fold rel into projection (optional relp*1/sqrt(32) scale) ----
__global__ void fold_k(const float* __restrict__ w, const float* __restrict__ b,
                       const float* __restrict__ rel, const float* __restrict__ scl,
                       float* __restrict__ Weff, float* __restrict__ beff)
{
  int idx = blockIdx.x*256 + threadIdx.x;
  if (idx >= NTYPE*DDIM*DDIM) return;
  int he = idx & 127, c = (idx >> 7) & 127, t = idx >> 14;
  int h = he >> 5, e = he & 31;
  float fs = scl ? scl[t*NHEAD + h]*0.17677669529663687f : 1.f;   // 1/sqrt(32)
  const float* wrow = w + (long)c*DDIM + h*HDIM;
  const float* relm = rel + ((long)(t*NHEAD + h)*HDIM)*HDIM + e;
  float s = 0.f;
  #pragma unroll 8
  for (int d=0; d<HDIM; d++) s += wrow[d] * relm[d*HDIM];
  Weff[(long)t*DDIM*DDIM + (long)c*DDIM + he] = s*fs;
  if (c == 0){
    float sb = 0.f;
    #pragma unroll 8
    for (int d=0; d<HDIM; d++) sb += b[h*HDIM+d] * relm[d*HDIM];
    beff[(long)t*DDIM + he] = sb*fs;
  }
}

// ---------------- HGT scores: all 3 types interleaved, q read once ------------------
__global__ __launch_bounds__(256) void hgt_score3_k(
    const int* __restrict__ rp, const int* __restrict__ srcs,
    const bfraw* __restrict__ qb, const bfraw* __restrict__ kt0,
    const bfraw* __restrict__ kt1, const bfraw* __restrict__ kt2,
    float* __restrict__ E)
{
  int node = blockIdx.x*8 + (threadIdx.x >> 5);
  int l = threadIdx.x & 31;
  int hd = l >> 3, sub = l & 7;
  float4 qv = ld_bf4(qb + (long)node*DDIM + l*4);
  float* E0 = E;
  float* E1 = E + (long)NEDGE*4;
  float* E2 = E + (long)2*NEDGE*4;
  const int* sp0 = srcs;
  const int* sp1 = srcs + NEDGE;
  const int* sp2 = srcs + (long)2*NEDGE;
  int p0 = rp[node],            e0 = rp[node+1];
  int p1 = rp[(NN+1)+node],     e1 = rp[(NN+1)+node+1];
  int p2 = rp[2*(NN+1)+node],   e2 = rp[2*(NN+1)+node+1];
  while (p0 < e0 || p1 < e1 || p2 < e2){
    bool b0a = p0 < e0, b0b = p0+1 < e0;
    bool b1a = p1 < e1, b1b = p1+1 < e1;
    bool b2a = p2 < e2, b2b = p2+1 < e2;
    int s0a = b0a ? sp0[p0]   : 0;
    int s0b = b0b ? sp0[p0+1] : 0;
    int s1a = b1a ? sp1[p1]   : 0;
    int s1b = b1b ? sp1[p1+1] : 0;
    int s2a = b2a ? sp2[p2]   : 0;
    int s2b = b2b ? sp2[p2+1] : 0;
    float4 k0a = ld_bf4(kt0 + (long)s0a*DDIM + l*4);
    float4 k0b = ld_bf4(kt0 + (long)s0b*DDIM + l*4);
    float4 k1a = ld_bf4(kt1 + (long)s1a*DDIM + l*4);
    float4 k1b = ld_bf4(kt1 + (long)s1b*DDIM + l*4);
    float4 k2a = ld_bf4(kt2 + (long)s2a*DDIM + l*4);
    float4 k2b = ld_bf4(kt2 + (long)s2b*DDIM + l*4);
    float d0a = qv.x*k0a.x + qv.y*k0a.y + qv.z*k0a.z + qv.w*k0a.w;
    float d0b = qv.x*k0b.x + qv.y*k0b.y + qv.z*k0b.z + qv.w*k0b.w;
    float d1a = qv.x*k1a.x + qv.y*k1a.y + qv.z*k1a.z + qv.w*k1a.w;
    float d1b = qv.x*k1b.x + qv.y*k1b.y + qv.z*k1b.z + qv.w*k1b.w;
    float d2a = qv.x*k2a.x + qv.y*k2a.y + qv.z*k2a.z + qv.w*k2a.w;
    float d2b = qv.x*k2b.x + qv.y*k2b.y + qv.z*k2b.z + qv.w*k2b.w;
    d0a += __shfl_xor(d0a, 1, 64); d0b += __shfl_xor(d0b, 1, 64);
    d1a += __shfl_xor(d1a, 1, 64); d1b += __shfl_xor(d1b, 1, 64);
    d2a += __shfl_xor(d2a, 1, 64); d2b += __shfl_xor(d2b, 1, 64);
    d0a += __shfl_xor(d0a, 2, 64); d0b += __shfl_xor(d0b, 2, 64);
    d1a += __shfl_xor(d1a, 2, 64); d1b += __shfl_xor(d1b, 2, 64);
    d2a += __shfl_xor(d2a, 2, 64); d2b += __shfl_xor(d2b, 2, 64);
    d0a += __shfl_xor(d0a, 4, 64); d0b += __shfl_xor(d0b, 4, 64);
    d1a += __shfl_xor(d1a, 4, 64); d1b += __shfl_xor(d1b, 4, 64);
    d2a += __shfl_xor(d2a, 4, 64); d2b += __shfl_xor(d2b, 4, 64);
    if (sub == 0){
      if (b0a) E0[(long)p0*4 + hd]     = __expf(d0a);
      if (b0b) E0[(long)(p0+1)*4 + hd] = __expf(d0b);
      if (b1a) E1[(long)p1*4 + hd]     = __expf(d1a);
      if (b1b) E1[(long)(p1+1)*4 + hd] = __expf(d1b);
      if (b2a) E2[(long)p2*4 + hd]     = __expf(d2a);
      if (b2b) E2[(long)(p2+1)*4 + hd] = __expf(d2b);
    }
    p0 += (b0a?1:0) + (b0b?1:0);
    p1 += (b1a?1:0) + (b1b?1:0);
    p2 += (b2a?1:0) + (b2b?1:0);
  }
}

// ---------------- HGT fused acc: 3 types interleaved, gelu finalize -> bf16 ---------
__global__ __launch_bounds__(256) void hgt_acc_fused_k(
    const int* __restrict__ rp, const int* __restrict__ srcs,
    const float* __restrict__ E, const bfraw* __restrict__ V0,
    const bfraw* __restrict__ V1, const bfraw* __restrict__ V2,
    bfraw* __restrict__ out)
{
  int node = blockIdx.x*8 + (threadIdx.x >> 5);
  int l = threadIdx.x & 31;
  int hd = l >> 3;
  const float* E0 = E;
  const float* E1 = E + (long)NEDGE*4;
  const float* E2 = E + (long)2*NEDGE*4;
  const int* sp0 = srcs;
  const int* sp1 = srcs + NEDGE;
  const int* sp2 = srcs + (long)2*NEDGE;
  int p0 = rp[node],            e0 = rp[node+1];
  int p1 = rp[(NN+1)+node],     e1 = rp[(NN+1)+node+1];
  int p2 = rp[2*(NN+1)+node],   e2 = rp[2*(NN+1)+node+1];
  float4 A0 = make_float4(0.f,0.f,0.f,0.f);
  float4 A1 = make_float4(0.f,0.f,0.f,0.f);
  float4 A2 = make_float4(0.f,0.f,0.f,0.f);
  float l0 = 0.f, l1 = 0.f, l2 = 0.f;
  while (p0 < e0 || p1 < e1 || p2 < e2){
    bool b0a = p0 < e0, b0b = p0+1 < e0;
    bool b1a = p1 < e1, b1b = p1+1 < e1;
    bool b2a = p2 < e2, b2b = p2+1 < e2;
    int s0a = b0a ? sp0[p0]   : 0;
    int s0b = b0b ? sp0[p0+1] : 0;
    int s1a = b1a ? sp1[p1]   : 0;
    int s1b = b1b ? sp1[p1+1] : 0;
    int s2a = b2a ? sp2[p2]   : 0;
    int s2b = b2b ? sp2[p2+1] : 0;
    long q0a = b0a ? (long)p0 : 0, q0b = b0b ? (long)(p0+1) : 0;
    long q1a = b1a ? (long)p1 : 0, q1b = b1b ? (long)(p1+1) : 0;
    long q2a = b2a ? (long)p2 : 0, q2b = b2b ? (long)(p2+1) : 0;
    float w0a = E0[q0a*4 + hd], w0b = E0[q0b*4 + hd];
    float w1a = E1[q1a*4 + hd], w1b = E1[q1b*4 + hd];
    float w2a = E2[q2a*4 + hd], w2b = E2[q2b*4 + hd];
    float4 g0a = ld_bf4(V0 + (long)s0a*DDIM + l*4);
    float4 g0b = ld_bf4(V0 + (long)s0b*DDIM + l*4);
    float4 g1a = ld_bf4(V1 + (long)s1a*DDIM + l*4);
    float4 g1b = ld_bf4(V1 + (long)s1b*DDIM + l*4);
    float4 g2a = ld_bf4(V2 + (long)s2a*DDIM + l*4);
    float4 g2b = ld_bf4(V2 + (long)s2b*DDIM + l*4);
    w0a = b0a ? w0a : 0.f; w0b = b0b ? w0b : 0.f;
    w1a = b1a ? w1a : 0.f; w1b = b1b ? w1b : 0.f;
    w2a = b2a ? w2a : 0.f; w2b = b2b ? w2b : 0.f;
    l0 += w0a + w0b; l1 += w1a + w1b; l2 += w2a + w2b;
    A0.x += w0a*g0a.x + w0b*g0b.x; A0.y += w0a*g0a.y + w0b*g0b.y;
    A0.z += w0a*g0a.z + w0b*g0b.z; A0.w += w0a*g0a.w + w0b*g0b.w;
    A1.x += w1a*g1a.x + w1b*g1b.x; A1.y += w1a*g1a.y + w1b*g1b.y;
    A1.z += w1a*g1a.z + w1b*g1b.z; A1.w += w1a*g1a.w + w1b*g1b.w;
    A2.x += w2a*g2a.x + w2b*g2b.x; A2.y += w2a*g2a.y + w2b*g2b.y;
    A2.z += w2a*g2a.z + w2b*g2b.z; A2.w += w2a*g2a.w + w2b*g2b.w;
    p0 += (b0a?1:0) + (b0b?1:0);
    p1 += (b1a?1:0) + (b1b?1:0);
    p2 += (b2a?1:0) + (b2b?1:0);
  }
  float lsum = l0 + l1 + l2;
  float inv = (lsum > 0.f) ? 1.f/lsum : 0.f;
  float o0 = gelu_f((A0.x+A1.x+A2.x)*inv), o1 = gelu_f((A0.y+A1.y+A2.y)*inv);
  float o2 = gelu_f((A0.z+A1.z+A2.z)*inv), o3 = gelu_f((A0.w+A1.w+A2.w)*inv);
  unsigned int lo = ((unsigned int)f2bf(o1) << 16) | f2bf(o0);
  unsigned int hi = ((unsigned int)f2bf(o3) << 16) | f2bf(o2);
  *reinterpret_cast<uint2*>(out + (long)node*DDIM + l*4) = make_uint2(lo, hi);
}

// ---------------- FiLM ----------------
__global__ void film1_k(const float* __restrict__ z, const float* __restrict__ w1,
                        const float* __restrict__ b1, float* __restrict__ f1)
{
  int idx = blockIdx.x*256 + threadIdx.x;
  if (idx >= NGRAPH*256) return;
  int j = idx & 255, b = idx >> 8;
  const float* zr = z + (long)b*DDIM;
  float s = b1[j];
  for (int k=0;k<DDIM;k++) s += zr[k] * w1[(long)k*256 + j];
  f1[idx] = gelu_f(s);
}

__global__ void film2_k(const float* __restrict__ f1, const float* __restrict__ w2,
                        const float* __restrict__ b2, float* __restrict__ gb)
{
  int idx = blockIdx.x*256 + threadIdx.x;
  if (idx >= NGRAPH*256) return;
  int j = idx & 255, b = idx >> 8;
  const float* fr = f1 + (long)b*256;
  float s = b2[j];
  for (int k=0;k<256;k++) s += fr[k] * w2[(long)k*256 + j];
  gb[idx] = 0.1f*tanhf(s);                       // pre-apply 0.1*tanh for epilogue
}

// ---------------- host ----------------
extern "C" void kernel_launch(void* const* d_in, const int* in_sizes, int n_in,
                              void* d_out, int out_size, void* d_ws, size_t ws_size,
                              hipStream_t stream)
{
  (void)in_sizes; (void)n_in; (void)out_size; (void)ws_size;
  const float* x_cell = (const float*)d_in[0];
  const float* x_emb  = (const float*)d_in[1];
  const float* z_h    = (const float*)d_in[2];
  const int*   ei     = (const int*)d_in[3];
  const float* gw[2]  = {(const float*)d_in[4],  (const float*)d_in[8]};
  const float* gas[2] = {(const float*)d_in[5],  (const float*)d_in[9]};
  const float* gad[2] = {(const float*)d_in[6],  (const float*)d_in[10]};
  const float* gbi[2] = {(const float*)d_in[7],  (const float*)d_in[11]};
  const float* norm1  = (const float*)d_in[12];
  const float* norm2  = (const float*)d_in[13];
  const float* norm3  = (const float*)d_in[14];
  const float* kw = (const float*)d_in[15]; const float* kb = (const float*)d_in[16];
  const float* qw = (const float*)d_in[17]; const float* qb = (const float*)d_in[18];
  const float* vw = (const float*)d_in[19]; const float* vb = (const float*)d_in[20];
  const float* relk = (const float*)d_in[21];
  const float* relv = (const float*)d_in[22];
  const float* relp = (const float*)d_in[23];
  const float* aw = (const float*)d_in[24]; const float* ab = (const float*)d_in[25];
  const float* skip = (const float*)d_in[26];
  const float* injw = (const float*)d_in[27]; const float* injb = (const float*)d_in[28];
  const float* fw1 = (const float*)d_in[29]; const float* fb1 = (const float*)d_in[30];
  const float* fw2 = (const float*)d_in[31]; const float* fb2 = (const float*)d_in[32];

  const long ND = (long)NN*DDIM;
  float* X    = (float*)d_ws;                    // x1 / x2 (f32)
  float* K    = X + ND;                          // 2x bf16 buffers
  bfraw* Xb   = (bfraw*)(K + ND);                // bf16 GEMM A; later HGT attn out
  bfraw* Hb   = Xb + ND;                         // bf16: h0 / kt0 / vt0
  float* Sbuf = (float*)(Hb + ND);               // GAT SS [T][N][8] | HGT E [3E][4]
  float* sA   = Sbuf + (long)NTYPE*NEDGE*4;      // spare
  float* sB   = sA + (long)NN*4;                 // spare
  float* WkE  = sB + (long)NN*4;
  float* bkE  = WkE + (long)NTYPE*DDIM*DDIM;
  float* WvE  = bkE + (long)NTYPE*DDIM;
  float* bvE  = WvE + (long)NTYPE*DDIM*DDIM;
  bfraw* Pswz = (bfraw*)(bvE + (long)NTYPE*DDIM);   // 2 layers x 4096 bf16
  bfraw* Wall = Pswz + (long)2*4096;                // 15 swizzled bf16 weights
  float* f1b  = (float*)(Wall + (long)15*16384);
  float* gbb  = f1b + (long)NGRAPH*256;
  int*   deg  = (int*)(gbb + (long)NGRAPH*256);  // 3N (reused as cnt)
  int*   rp   = deg + (long)NTYPE*NN;            // 3(N+1)
  int*   srcs = rp  + (long)NTYPE*(NN+1);        // 3E
  int*   csum = srcs + (long)NTYPE*NEDGE;        // 192

  bfraw* Kb0 = (bfraw*)K;                        // K as 2 bf16 buffers
  bfraw* Kb1 = Kb0 + ND;
  bfraw* qscr = (bfraw*)d_out;                   // d_out as q scratch (32 of 64 MB)

  const dim3 b256(256);
  float* NF = nullptr;
  bfraw* NB = nullptr; (void)sA; (void)sB;

  // ---------- CSR build ----------
  fill_k<<<256, b256, 0, stream>>>((float*)deg, 0.f, NTYPE*NN);
  hist_k<<<(NTYPE*NEDGE)/256, b256, 0, stream>>>(ei, deg);
  scan_a_k<<<dim3(64, NTYPE), b256, 0, stream>>>(deg, rp, csum);
  scan_b_k<<<NTYPE, 64, 0, stream>>>(csum);
  scan_c_k<<<dim3(64, NTYPE), b256, 0, stream>>>(rp, csum);
  fill_k<<<256, b256, 0, stream>>>((float*)deg, 0.f, NTYPE*NN);   // cnt
  scatter_k<<<(NTYPE*NEDGE)/256, b256, 0, stream>>>(ei, rp, deg, srcs);

  // ---------- weight prep ----------
  fold_k<<<(NTYPE*DDIM*DDIM)/256, b256, 0, stream>>>(kw, kb, relk, relp, WkE, bkE);
  fold_k<<<(NTYPE*DDIM*DDIM)/256, b256, 0, stream>>>(vw, vb, relv, NF, WvE, bvE);
  wswz_k<<<dim3(64, 15), b256, 0, stream>>>(
      gw[0], gw[0]+16384, gw[0]+32768,
      gw[1], gw[1]+16384, gw[1]+32768,
      qw, WkE, WvE, aw, injw, Wall);
  gatproj_k<<<16, b256, 0, stream>>>(gw[0], gas[0], gad[0], Pswz);
  gatproj_k<<<16, b256, 0, stream>>>(gw[1], gas[1], gad[1], Pswz + 4096);

  // ---------- FiLM (independent, run early) ----------
  film1_k<<<(NGRAPH*256)/256, b256, 0, stream>>>(z_h, fw1, fb1, f1b);
  film2_k<<<(NGRAPH*256)/256, b256, 0, stream>>>(f1b, fw2, fb2, gbb);

  // ---------- GAT layers ----------
  for (int layer=0; layer<2; layer++){
    gemm3_k<<<NN/128, b256, 0, stream>>>(
        Xb, (layer==0) ? x_cell : NF,
        Wall + (long)(layer*3+0)*16384, Wall + (long)(layer*3+1)*16384,
        Wall + (long)(layer*3+2)*16384,
        NF, NF, NF,
        Hb, Kb0, Kb1,
        Pswz + (long)layer*4096, Sbuf,
        NB, NF, NB);
    gat_fused_k<<<NN/8, b256, 0, stream>>>(
        rp, srcs, Hb, Kb0, Kb1, Sbuf, gbi[layer],
        (layer==0) ? x_cell : X, (layer==0) ? norm1 : norm2, X, Xb);
  }

  // ---------- HGT ----------
  // kt0->Hb, kt1->Kb0, kt2->Kb1, q->qscr (d_out scratch) — A read once
  gemm3_k<<<NN/128, b256, 0, stream>>>(
      Xb, NF,
      Wall + (long)7*16384, Wall + (long)8*16384, Wall + (long)9*16384,
      bkE, bkE + DDIM, bkE + 2*DDIM,
      Hb, Kb0, Kb1,
      NB, NF,
      Wall + (long)6*16384, qb, qscr);
  hgt_score3_k<<<NN/8, b256, 0, stream>>>(rp, srcs, qscr, Hb, Kb0, Kb1, Sbuf);
  // vt0..2 -> Hb, Kb0, Kb1 (kt dead), A read once
  gemm3_k<<<NN/128, b256, 0, stream>>>(
      Xb, NF,
      Wall + (long)10*16384, Wall + (long)11*16384, Wall + (long)12*16384,
      bvE, bvE + DDIM, bvE + 2*DDIM,
      Hb, Kb0, Kb1,
      NB, NF, NB, NF, NB);
  hgt_acc_fused_k<<<NN/8, b256, 0, stream>>>(rp, srcs, Sbuf, Hb, Kb0, Kb1, Xb);
  // fused: GEMM(attn@aw) + res3 + GEMM(x_emb@injw) + FiLM -> out (x3 never stored)
  gemm_r3film_k<<<NN/128, b256, 0, stream>>>(
      Xb, Wall + (long)13*16384, ab, X, norm3, skip,
      x_emb, Wall + (long)14*16384, injb, gbb, (float*)d_out);
}

// Round 5
// 869.771 us; speedup vs baseline: 1.0233x; 1.0233x over previous
//
#include <hip/hip_runtime.h>
#include <math.h>
#include <cstdint>

// ---------------- problem constants ----------------
#define NN     131072     // nodes
#define DDIM   128        // hidden dim
#define NHEAD  4
#define HDIM   32
#define NTYPE  3
#define NEDGE  262144     // edges per type (2^18)
#define NGRAPH 512
#define EPSV   1e-6f
#define SLOPEV 0.2f

typedef unsigned short bfraw;
typedef __attribute__((ext_vector_type(8))) short bf16x8;
typedef __attribute__((ext_vector_type(4))) float f32x4;

// ---------------- helpers ----------------
__device__ __forceinline__ float lrelu(float x){ return x >= 0.f ? x : SLOPEV*x; }
__device__ __forceinline__ float gelu_f(float x){ return 0.5f*x*(1.f+erff(x*0.70710678118654752f)); }
__device__ __forceinline__ bfraw f2bf(float f){
  unsigned int u = __float_as_uint(f);
  u += 0x7fffu + ((u >> 16) & 1u);          // RNE
  return (bfraw)(u >> 16);
}
__device__ __forceinline__ float4 ld_bf4(const bfraw* p){
  uint2 u = *reinterpret_cast<const uint2*>(p);
  float4 r;
  r.x = __uint_as_float(u.x << 16); r.y = __uint_as_float(u.x & 0xffff0000u);
  r.z = __uint_as_float(u.y << 16); r.w = __uint_as_float(u.y & 0xffff0000u);
  return r;
}
__device__ __forceinline__ bf16x8 pack_bf8(const float* p){
  float4 u = *reinterpret_cast<const float4*>(p);
  float4 v = *reinterpret_cast<const float4*>(p+4);
  bf16x8 r;
  r[0]=(short)f2bf(u.x); r[1]=(short)f2bf(u.y); r[2]=(short)f2bf(u.z); r[3]=(short)f2bf(u.w);
  r[4]=(short)f2bf(v.x); r[5]=(short)f2bf(v.y); r[6]=(short)f2bf(v.z); r[7]=(short)f2bf(v.w);
  return r;
}

// ---------------- generic fill ----------------
__global__ void fill_k(float* __restrict__ p, float v, int n){
  int i = blockIdx.x*blockDim.x + threadIdx.x;
  int stride = gridDim.x*blockDim.x;
  for (; i < n; i += stride) p[i] = v;
}

// ---------------- CSR build (dst-sorted, per edge type) ----------------
__global__ void hist_k(const int* __restrict__ ei, int* __restrict__ deg){
  int idx = blockIdx.x*256 + threadIdx.x;          // < 3E
  int t = idx >> 18, e = idx & (NEDGE-1);
  int d = ei[(long)t*2*NEDGE + NEDGE + e];
  atomicAdd(&deg[t*NN + d], 1);
}

__global__ void scan_a_k(const int* __restrict__ deg, int* __restrict__ rp,
                         int* __restrict__ csum){
  __shared__ int sh[256];
  int t = blockIdx.y, chunk = blockIdx.x, tid = threadIdx.x;
  const int* dp = deg + (long)t*NN + chunk*2048 + tid*8;
  int v[8]; int s = 0;
  #pragma unroll
  for (int i=0;i<8;i++){ v[i] = dp[i]; s += v[i]; }
  sh[tid] = s; __syncthreads();
  for (int off=1; off<256; off<<=1){
    int x = (tid>=off) ? sh[tid-off] : 0;
    __syncthreads();
    sh[tid] += x;
    __syncthreads();
  }
  int run = sh[tid] - s;                            // exclusive prefix
  int* op = rp + (long)t*(NN+1) + chunk*2048 + tid*8;
  #pragma unroll
  for (int i=0;i<8;i++){ op[i] = run; run += v[i]; }
  if (tid == 255) csum[t*64 + chunk] = sh[255];
}

__global__ void scan_b_k(int* __restrict__ csum){
  __shared__ int sh[64];
  int t = blockIdx.x, tid = threadIdx.x;
  int s = csum[t*64 + tid];
  sh[tid] = s; __syncthreads();
  for (int off=1; off<64; off<<=1){
    int x = (tid>=off) ? sh[tid-off] : 0;
    __syncthreads();
    sh[tid] += x;
    __syncthreads();
  }
  csum[t*64 + tid] = sh[tid] - s;                   // exclusive
}

__global__ void scan_c_k(int* __restrict__ rp, const int* __restrict__ csum){
  int t = blockIdx.y, chunk = blockIdx.x, tid = threadIdx.x;
  int add = csum[t*64 + chunk];
  int* op = rp + (long)t*(NN+1) + chunk*2048 + tid*8;
  #pragma unroll
  for (int i=0;i<8;i++) op[i] += add;
  if (chunk == 63 && tid == 255) rp[(long)t*(NN+1) + NN] = NEDGE;
}

__global__ void scatter_k(const int* __restrict__ ei, const int* __restrict__ rp,
                          int* __restrict__ cnt, int* __restrict__ srcs){
  int idx = blockIdx.x*256 + threadIdx.x;          // < 3E
  int t = idx >> 18, e = idx & (NEDGE-1);
  int s = ei[(long)t*2*NEDGE + e];
  int d = ei[(long)t*2*NEDGE + NEDGE + e];
  int pos = rp[(long)t*(NN+1) + d] + atomicAdd(&cnt[t*NN + d], 1);
  srcs[(long)t*NEDGE + pos] = s;
}

// ---------------- weight swizzle: f32 [128,128] -> bf16 b-frag layout ----------------
__global__ void wswz_k(const float* g0a, const float* g0b, const float* g0c,
                       const float* g1a, const float* g1b, const float* g1c,
                       const float* qw,
                       const float* wk, const float* wv,   // [3][128][128] each
                       const float* aw, const float* injw,
                       bfraw* __restrict__ Wall)
{
  int y = blockIdx.y;
  const float* src;
  switch(y){
    case 0: src = g0a; break;  case 1: src = g0b; break;  case 2: src = g0c; break;
    case 3: src = g1a; break;  case 4: src = g1b; break;  case 5: src = g1c; break;
    case 6: src = qw; break;
    case 7: case 8: case 9: src = wk + (long)(y-7)*16384; break;
    case 10: case 11: case 12: src = wv + (long)(y-10)*16384; break;
    case 13: src = aw; break;
    default: src = injw; break;
  }
  int i = blockIdx.x*256 + threadIdx.x;            // < 16384
  int j = i & 7, lane = (i>>3) & 63, kc = (i>>9) & 3, nt = i >> 11;
  int k = kc*32 + ((lane>>4)<<3) + j;
  int n = nt*16 + (lane & 15);
  Wall[(long)y*16384 + i] = f2bf(src[k*DDIM + n]);
}

// ---------------- GAT score projection, directly in swizzled b-frag layout ----------
__global__ void gatproj_k(const float* __restrict__ w, const float* __restrict__ asrc,
                          const float* __restrict__ adst, bfraw* __restrict__ out)
{
  int i = blockIdx.x*256 + threadIdx.x;            // < 4096
  int j = i & 7, lane = (i>>3) & 63, kc = (i>>9) & 3, nt = i >> 11;   // nt 0..1
  int k = kc*32 + ((lane>>4)<<3) + j;
  int n = nt*16 + (lane & 15);
  float s = 0.f;
  if (n < 24){
    int t = n >> 3, sd = (n >> 2) & 1, hh = n & 3;
    const float* a  = (sd ? adst : asrc) + ((long)t*NHEAD + hh)*HDIM;
    const float* wr = w + ((long)t*DDIM + k)*DDIM + hh*HDIM;
    #pragma unroll 8
    for (int dd=0; dd<HDIM; dd++) s += wr[dd]*a[dd];
  }
  out[i] = f2bf(s);
}

// ---------------- MFMA GEMM building blocks -----------------------------------------
__device__ __forceinline__ void load_afrags_bf16(const bfraw* __restrict__ A,
    long blockRow, int tid, bf16x8 a0[4], bf16x8 a1[4])
{
  const int w = tid >> 6, lane = tid & 63;
  const long rowA = blockRow + w*32 + (lane & 15);
  const bfraw* A0 = A + rowA*DDIM + ((lane>>4)<<3);
  #pragma unroll
  for (int kc=0;kc<4;kc++){
    a0[kc] = *reinterpret_cast<const bf16x8*>(A0 + kc*32);
    a1[kc] = *reinterpret_cast<const bf16x8*>(A0 + 16*DDIM + kc*32);
  }
}

__device__ __forceinline__ void load_afrags_f32(const float* __restrict__ A,
    long blockRow, int tid, bf16x8 a0[4], bf16x8 a1[4])
{
  const int w = tid >> 6, lane = tid & 63;
  const long rowA = blockRow + w*32 + (lane & 15);
  const float* A0 = A + rowA*DDIM + ((lane>>4)<<3);
  #pragma unroll
  for (int kc=0;kc<4;kc++){
    a0[kc] = pack_bf8(A0 + kc*32);
    a1[kc] = pack_bf8(A0 + 16*DDIM + kc*32);
  }
}

__device__ __forceinline__ void mfma_128(const bfraw* Wl, int lane,
    bf16x8 a0[4], bf16x8 a1[4], f32x4 acc0[8], f32x4 acc1[8])
{
  const f32x4 zz = {0.f,0.f,0.f,0.f};
  #pragma unroll
  for (int nt=0;nt<8;nt++){ acc0[nt]=zz; acc1[nt]=zz; }
  #pragma unroll
  for (int nt=0;nt<8;nt++){
    #pragma unroll
    for (int kc=0;kc<4;kc++){
      bf16x8 b = *reinterpret_cast<const bf16x8*>(Wl + ((nt*4+kc)*64 + lane)*8);
      acc0[nt] = __builtin_amdgcn_mfma_f32_16x16x32_bf16(a0[kc], b, acc0[nt], 0, 0, 0);
      acc1[nt] = __builtin_amdgcn_mfma_f32_16x16x32_bf16(a1[kc], b, acc1[nt], 0, 0, 0);
    }
  }
}

__device__ __forceinline__ void gemm_store_bf16(f32x4 acc0[8], f32x4 acc1[8],
    const float* bias, bfraw* __restrict__ Cb, long blockRow, int tid)
{
  const int w = tid>>6, lane = tid&63, q = lane>>4;
  #pragma unroll
  for (int g=0; g<2; g++){
    #pragma unroll
    for (int nt=0;nt<8;nt++){
      int col = nt*16 + (lane & 15);
      float bv = bias ? bias[col] : 0.f;
      #pragma unroll
      for (int r=0;r<4;r++){
        long row = blockRow + w*32 + g*16 + q*4 + r;
        float v = (g ? acc1[nt][r] : acc0[nt][r]) + bv;
        Cb[row*DDIM + col] = f2bf(v);
      }
    }
  }
}

// ---- up to 4 GEMMs sharing one A-read (+ optional 24-col score GEMM tail) ----------
__global__ __launch_bounds__(256) void gemm3_k(
    const bfraw* __restrict__ Ab, const float* __restrict__ Af,
    const bfraw* __restrict__ W0, const bfraw* __restrict__ W1,
    const bfraw* __restrict__ W2,
    const float* __restrict__ b0, const float* __restrict__ b1,
    const float* __restrict__ b2,
    bfraw* __restrict__ O0, bfraw* __restrict__ O1, bfraw* __restrict__ O2,
    const bfraw* __restrict__ Psw, float* __restrict__ SS,
    const bfraw* __restrict__ W3, const float* __restrict__ b3,
    bfraw* __restrict__ O3)
{
  __shared__ bfraw Wl[16384];
  const int tid = threadIdx.x;
  const long blockRow = (long)blockIdx.x * 128;
  const int w = tid >> 6, lane = tid & 63;
  bf16x8 a0[4], a1[4];
  if (Af) load_afrags_f32(Af, blockRow, tid, a0, a1);
  else    load_afrags_bf16(Ab, blockRow, tid, a0, a1);
  const bfraw* Ws[3] = {W0, W1, W2};
  const float* bs[3] = {b0, b1, b2};
  bfraw* Os[3] = {O0, O1, O2};
  #pragma unroll
  for (int t=0;t<3;t++){
    __syncthreads();                                 // prev readers done
    #pragma unroll
    for (int i=0;i<8;i++)
      *reinterpret_cast<uint4*>(Wl + (i*256+tid)*8) =
          *reinterpret_cast<const uint4*>(Ws[t] + (i*256+tid)*8);
    __syncthreads();
    f32x4 acc0[8], acc1[8];
    mfma_128(Wl, lane, a0, a1, acc0, acc1);
    gemm_store_bf16(acc0, acc1, bs[t], Os[t], blockRow, tid);
  }
  if (W3){
    __syncthreads();
    #pragma unroll
    for (int i=0;i<8;i++)
      *reinterpret_cast<uint4*>(Wl + (i*256+tid)*8) =
          *reinterpret_cast<const uint4*>(W3 + (i*256+tid)*8);
    __syncthreads();
    f32x4 acc0[8], acc1[8];
    mfma_128(Wl, lane, a0, a1, acc0, acc1);
    gemm_store_bf16(acc0, acc1, b3, O3, blockRow, tid);
  }
  if (Psw){
    __syncthreads();
    #pragma unroll
    for (int i=0;i<2;i++)
      *reinterpret_cast<uint4*>(Wl + (i*256+tid)*8) =
          *reinterpret_cast<const uint4*>(Psw + (i*256+tid)*8);
    __syncthreads();
    const f32x4 zz = {0.f,0.f,0.f,0.f};
    f32x4 acc0[2], acc1[2];
    #pragma unroll
    for (int nt=0;nt<2;nt++){ acc0[nt]=zz; acc1[nt]=zz; }
    #pragma unroll
    for (int nt=0;nt<2;nt++){
      #pragma unroll
      for (int kc=0;kc<4;kc++){
        bf16x8 b = *reinterpret_cast<const bf16x8*>(Wl + ((nt*4+kc)*64 + lane)*8);
        acc0[nt] = __builtin_amdgcn_mfma_f32_16x16x32_bf16(a0[kc], b, acc0[nt], 0, 0, 0);
        acc1[nt] = __builtin_amdgcn_mfma_f32_16x16x32_bf16(a1[kc], b, acc1[nt], 0, 0, 0);
      }
    }
    const int q = lane >> 4;
    #pragma unroll
    for (int g=0; g<2; g++){
      #pragma unroll
      for (int nt=0;nt<2;nt++){
        int col = nt*16 + (lane & 15);
        if (col < 24){
          int tt = col >> 3, c = col & 7;           // SS layout [T][NN][8]
          #pragma unroll
          for (int r=0;r<4;r++){
            long row = blockRow + w*32 + g*16 + q*4 + r;
            SS[(((long)tt*NN + row)<<3) + c] = (g ? acc1[nt][r] : acc0[nt][r]);
          }
        }
      }
    }
  }
}

// ---- fused: GEMM(attn@aw) + res3 + GEMM(x_emb@injw) + FiLM -> out ------------------
__global__ __launch_bounds__(256) void gemm_r3film_k(
    const bfraw* __restrict__ Aattn, const bfraw* __restrict__ Waw,
    const float* __restrict__ ab, const float* __restrict__ X,
    const float* __restrict__ norm, const float* __restrict__ skip,
    const float* __restrict__ xemb, const bfraw* __restrict__ Winj,
    const float* __restrict__ injb, const float* __restrict__ gbt,
    float* __restrict__ out)
{
  __shared__ bfraw Wl[16384];
  const int tid = threadIdx.x;
  const long blockRow = (long)blockIdx.x * 128;
  // GEMM1: attn-out @ aw
  #pragma unroll
  for (int i=0;i<8;i++)
    *reinterpret_cast<uint4*>(Wl + (i*256+tid)*8) =
        *reinterpret_cast<const uint4*>(Waw + (i*256+tid)*8);
  __syncthreads();
  bf16x8 a0[4], a1[4];
  load_afrags_bf16(Aattn, blockRow, tid, a0, a1);
  f32x4 accA0[8], accA1[8];
  mfma_128(Wl, tid & 63, a0, a1, accA0, accA1);
  __syncthreads();
  // GEMM2: x_emb(f32) @ injw
  #pragma unroll
  for (int i=0;i<8;i++)
    *reinterpret_cast<uint4*>(Wl + (i*256+tid)*8) =
        *reinterpret_cast<const uint4*>(Winj + (i*256+tid)*8);
  __syncthreads();
  load_afrags_f32(xemb, blockRow, tid, a0, a1);
  f32x4 accB0[8], accB1[8];
  mfma_128(Wl, tid & 63, a0, a1, accB0, accB1);
  // epilogue
  const int w = tid>>6, lane = tid&63, q = lane>>4;
  const float gsk = 1.f/(1.f + __expf(-skip[0]));
  #pragma unroll
  for (int g=0; g<2; g++){
    #pragma unroll
    for (int r=0;r<4;r++){
      long row = blockRow + w*32 + g*16 + q*4 + r;
      float vv[8], xx[8];
      float sq = 0.f;
      #pragma unroll
      for (int nt=0;nt<8;nt++){
        int col = nt*16 + (lane & 15);
        float oA = (g ? accA1[nt][r] : accA0[nt][r]) + ab[col];
        float xo = X[row*DDIM + col];
        float v  = gsk*oA + (1.f-gsk)*xo;
        vv[nt] = v; xx[nt] = xo; sq += v*v;
      }
      sq += __shfl_xor(sq, 1, 64);
      sq += __shfl_xor(sq, 2, 64);
      sq += __shfl_xor(sq, 4, 64);
      sq += __shfl_xor(sq, 8, 64);
      float rr = rsqrtf(sq*(1.f/DDIM) + EPSV);
      long gi = row >> 8;                             // 256 nodes per graph
      #pragma unroll
      for (int nt=0;nt<8;nt++){
        int col = nt*16 + (lane & 15);
        float x3 = lrelu(xx[nt] + norm[col]*vv[nt]*rr);
        float vB = (g ? accB1[nt][r] : accB0[nt][r]) + injb[col] + x3;
        out[row*DDIM + col] = (1.f + gbt[gi*256 + col])*vB + gbt[gi*256 + 128 + col];
      }
    }
  }
}

// ---------------- fused GAT: 3-type exp-softmax agg + bias + RMS + residual ---------
// Sequential per-type, 2-wide dual chains (round-3 proven structure).
// SS layout: [T][NN][8], cols 0..3 = ss per head, 4..7 = ds per head.
__global__ __launch_bounds__(256) void gat_fused_k(
    const int* __restrict__ rp, const int* __restrict__ srcs,
    const bfraw* __restrict__ H0, const bfraw* __restrict__ H1,
    const bfraw* __restrict__ H2, const float* __restrict__ SS,
    const float* __restrict__ gatb, const float* __restrict__ xold,
    const float* __restrict__ norm, float* __restrict__ X, bfraw* __restrict__ Xb)
{
  int node = blockIdx.x*8 + (threadIdx.x >> 5);
  int l = threadIdx.x & 31;
  int hd = l >> 3;
  const bfraw* Hs[3] = {H0, H1, H2};
  // hoist all per-type self data + ranges (independent loads issue together)
  float dsv[3], ssl[3]; float4 hsl[3]; int beg[3], end[3];
  #pragma unroll
  for (int t=0; t<3; t++){
    const float* St = SS + ((long)t*NN)*8;
    dsv[t] = St[(long)node*8 + 4 + hd];
    ssl[t] = St[(long)node*8 + hd];
    hsl[t] = ld_bf4(Hs[t] + (long)node*DDIM + l*4);
    beg[t] = rp[t*(NN+1) + node];
    end[t] = rp[t*(NN+1) + node + 1];
  }
  float tx=0.f, ty=0.f, tz=0.f, tw=0.f;
  #pragma unroll
  for (int t=0; t<3; t++){
    const bfraw* Ht = Hs[t];
    const float* St = SS + ((long)t*NN)*8;
    const int* sp = srcs + (long)t*NEDGE;
    const float d = dsv[t];
    float e = __expf(lrelu(ssl[t] + d));             // self-loop
    float lA = e, lB = 0.f;
    float4 aA = make_float4(e*hsl[t].x, e*hsl[t].y, e*hsl[t].z, e*hsl[t].w);
    float4 aB = make_float4(0.f,0.f,0.f,0.f);
    int p = beg[t];
    for (; p+1 < end[t]; p += 2){                    // 2-wide: dual chains
      int s0 = sp[p], s1 = sp[p+1];
      float v0 = St[(long)s0*8 + hd];
      float v1 = St[(long)s1*8 + hd];
      float4 h0 = ld_bf4(Ht + (long)s0*DDIM + l*4);
      float4 h1 = ld_bf4(Ht + (long)s1*DDIM + l*4);
      float e0 = __expf(lrelu(v0 + d));
      float e1 = __expf(lrelu(v1 + d));
      lA += e0; lB += e1;
      aA.x += e0*h0.x; aA.y += e0*h0.y; aA.z += e0*h0.z; aA.w += e0*h0.w;
      aB.x += e1*h1.x; aB.y += e1*h1.y; aB.z += e1*h1.z; aB.w += e1*h1.w;
    }
    if (p < end[t]){
      int s0 = sp[p];
      float e0 = __expf(lrelu(St[(long)s0*8 + hd] + d));
      float4 h0 = ld_bf4(Ht + (long)s0*DDIM + l*4);
      lA += e0;
      aA.x += e0*h0.x; aA.y += e0*h0.y; aA.z += e0*h0.z; aA.w += e0*h0.w;
    }
    float inv = 1.f/(lA + lB);
    tx += (aA.x+aB.x)*inv; ty += (aA.y+aB.y)*inv;
    tz += (aA.z+aB.z)*inv; tw += (aA.w+aB.w)*inv;
  }
  int f = l*4;
  tx += gatb[f]   + gatb[DDIM+f]   + gatb[2*DDIM+f];
  ty += gatb[f+1] + gatb[DDIM+f+1] + gatb[2*DDIM+f+1];
  tz += gatb[f+2] + gatb[DDIM+f+2] + gatb[2*DDIM+f+2];
  tw += gatb[f+3] + gatb[DDIM+f+3] + gatb[2*DDIM+f+3];
  float sq = tx*tx + ty*ty + tz*tz + tw*tw;
  sq += __shfl_xor(sq, 1, 64);
  sq += __shfl_xor(sq, 2, 64);
  sq += __shfl_xor(sq, 4, 64);
  sq += __shfl_xor(sq, 8, 64);
  sq += __shfl_xor(sq, 16, 64);
  float r = rsqrtf(sq*(1.f/DDIM) + EPSV);
  float4 x4 = *reinterpret_cast<const float4*>(xold + (long)node*DDIM + f);
  float4 o;
  o.x = lrelu(x4.x + norm[f]  *tx*r);
  o.y = lrelu(x4.y + norm[f+1]*ty*r);
  o.z = lrelu(x4.z + norm[f+2]*tz*r);
  o.w = lrelu(x4.w + norm[f+3]*tw*r);
  *reinterpret_cast<float4*>(X + (long)node*DDIM + f) = o;
  unsigned int lo = ((unsigned int)f2bf(o.y) << 16) | f2bf(o.x);
  unsigned int hi = ((unsigned int)f2bf(o.w) << 16) | f2bf(o.z);
  *reinterpret_cast<uint2*>(Xb + (long)node*DDIM + f) = make_uint2(lo, hi);
}

// ---------------- HGT: fold rel into projection (optional relp*1/sqrt(32) scale) ----
__global__ void fold_k(const float* __restrict__ w, const float* __restrict__ b,
                       const float* __restrict__ rel, const float* __restrict__ scl,
                       float* __restrict__ Weff, float* __restrict__ beff)
{
  int idx = blockIdx.x*256 + threadIdx.x;
  if (idx >= NTYPE*DDIM*DDIM) return;
  int he = idx & 127, c = (idx >> 7) & 127, t = idx >> 14;
  int h = he >> 5, e = he & 31;
  float fs = scl ? scl[t*NHEAD + h]*0.17677669529663687f : 1.f;   // 1/sqrt(32)
  const float* wrow = w + (long)c*DDIM + h*HDIM;
  const float* relm = rel + ((long)(t*NHEAD + h)*HDIM)*HDIM + e;
  float s = 0.f;
  #pragma unroll 8
  for (int d=0; d<HDIM; d++) s += wrow[d] * relm[d*HDIM];
  Weff[(long)t*DDIM*DDIM + (long)c*DDIM + he] = s*fs;
  if (c == 0){
    float sb = 0.f;
    #pragma unroll 8
    for (int d=0; d<HDIM; d++) sb += b[h*HDIM+d] * relm[d*HDIM];
    beff[(long)t*DDIM + he] = sb*fs;
  }
}

// ---------------- HGT scores: 3 types sequential, q read once, 2-wide ---------------
__global__ __launch_bounds__(256) void hgt_score3_k(
    const int* __restrict__ rp, const int* __restrict__ srcs,
    const bfraw* __restrict__ qb, const bfraw* __restrict__ kt0,
    const bfraw* __restrict__ kt1, const bfraw* __restrict__ kt2,
    float* __restrict__ E)
{
  int node = blockIdx.x*8 + (threadIdx.x >> 5);
  int l = threadIdx.x & 31;
  int hd = l >> 3, sub = l & 7;
  float4 qv = ld_bf4(qb + (long)node*DDIM + l*4);
  const bfraw* kts[3] = {kt0, kt1, kt2};
  #pragma unroll
  for (int t=0; t<3; t++){
    const bfraw* kt = kts[t];
    const int* sp = srcs + (long)t*NEDGE;
    float* Et = E + (long)t*NEDGE*4;
    int beg = rp[t*(NN+1) + node], end = rp[t*(NN+1) + node + 1];
    int p = beg;
    for (; p+1 < end; p += 2){
      int s0 = sp[p], s1 = sp[p+1];
      float4 k0 = ld_bf4(kt + (long)s0*DDIM + l*4);
      float4 k1 = ld_bf4(kt + (long)s1*DDIM + l*4);
      float d0 = qv.x*k0.x + qv.y*k0.y + qv.z*k0.z + qv.w*k0.w;
      float d1 = qv.x*k1.x + qv.y*k1.y + qv.z*k1.z + qv.w*k1.w;
      d0 += __shfl_xor(d0, 1, 64);  d1 += __shfl_xor(d1, 1, 64);
      d0 += __shfl_xor(d0, 2, 64);  d1 += __shfl_xor(d1, 2, 64);
      d0 += __shfl_xor(d0, 4, 64);  d1 += __shfl_xor(d1, 4, 64);
      if (sub == 0){
        Et[(long)p*4 + hd]     = __expf(d0);
        Et[(long)(p+1)*4 + hd] = __expf(d1);
      }
    }
    if (p < end){
      int s0 = sp[p];
      float4 k0 = ld_bf4(kt + (long)s0*DDIM + l*4);
      float d0 = qv.x*k0.x + qv.y*k0.y + qv.z*k0.z + qv.w*k0.w;
      d0 += __shfl_xor(d0, 1, 64);
      d0 += __shfl_xor(d0, 2, 64);
      d0 += __shfl_xor(d0, 4, 64);
      if (sub == 0) Et[(long)p*4 + hd] = __expf(d0);
    }
  }
}

// ---------------- HGT fused acc: 3 types sequential, dual chains, gelu -> bf16 ------
__global__ __launch_bounds__(256) void hgt_acc_fused_k(
    const int* __restrict__ rp, const int* __restrict__ srcs,
    const float* __restrict__ E, const bfraw* __restrict__ V0,
    const bfraw* __restrict__ V1, const bfraw* __restrict__ V2,
    bfraw* __restrict__ out)
{
  int node = blockIdx.x*8 + (threadIdx.x >> 5);
  int l = threadIdx.x & 31;
  int hd = l >> 3;
  float axA=0.f, ayA=0.f, azA=0.f, awA=0.f, lsA=0.f;
  float axB=0.f, ayB=0.f, azB=0.f, awB=0.f, lsB=0.f;
  const bfraw* Vs[3] = {V0, V1, V2};
  #pragma unroll
  for (int t=0; t<3; t++){
    const bfraw* Vt = Vs[t];
    const float* Ep = E + (long)t*NEDGE*4;
    const int* sp = srcs + (long)t*NEDGE;
    int beg = rp[t*(NN+1) + node], end = rp[t*(NN+1) + node + 1];
    int p = beg;
    for (; p+1 < end; p += 2){
      int s0 = sp[p], s1 = sp[p+1];
      float e0 = Ep[(long)p*4 + hd];
      float e1 = Ep[(long)(p+1)*4 + hd];
      float4 v0 = ld_bf4(Vt + (long)s0*DDIM + l*4);
      float4 v1 = ld_bf4(Vt + (long)s1*DDIM + l*4);
      axA += e0*v0.x; ayA += e0*v0.y; azA += e0*v0.z; awA += e0*v0.w; lsA += e0;
      axB += e1*v1.x; ayB += e1*v1.y; azB += e1*v1.z; awB += e1*v1.w; lsB += e1;
    }
    if (p < end){
      int s0 = sp[p];
      float e0 = Ep[(long)p*4 + hd];
      float4 v0 = ld_bf4(Vt + (long)s0*DDIM + l*4);
      axA += e0*v0.x; ayA += e0*v0.y; azA += e0*v0.z; awA += e0*v0.w; lsA += e0;
    }
  }
  float lsum = lsA + lsB;
  float inv = (lsum > 0.f) ? 1.f/lsum : 0.f;
  float o0 = gelu_f((axA+axB)*inv), o1 = gelu_f((ayA+ayB)*inv);
  float o2 = gelu_f((azA+azB)*inv), o3 = gelu_f((awA+awB)*inv);
  unsigned int lo = ((unsigned int)f2bf(o1) << 16) | f2bf(o0);
  unsigned int hi = ((unsigned int)f2bf(o3) << 16) | f2bf(o2);
  *reinterpret_cast<uint2*>(out + (long)node*DDIM + l*4) = make_uint2(lo, hi);
}

// ---------------- FiLM ----------------
__global__ void film1_k(const float* __restrict__ z, const float* __restrict__ w1,
                        const float* __restrict__ b1, float* __restrict__ f1)
{
  int idx = blockIdx.x*256 + threadIdx.x;
  if (idx >= NGRAPH*256) return;
  int j = idx & 255, b = idx >> 8;
  const float* zr = z + (long)b*DDIM;
  float s = b1[j];
  for (int k=0;k<DDIM;k++) s += zr[k] * w1[(long)k*256 + j];
  f1[idx] = gelu_f(s);
}

__global__ void film2_k(const float* __restrict__ f1, const float* __restrict__ w2,
                        const float* __restrict__ b2, float* __restrict__ gb)
{
  int idx = blockIdx.x*256 + threadIdx.x;
  if (idx >= NGRAPH*256) return;
  int j = idx & 255, b = idx >> 8;
  const float* fr = f1 + (long)b*256;
  float s = b2[j];
  for (int k=0;k<256;k++) s += fr[k] * w2[(long)k*256 + j];
  gb[idx] = 0.1f*tanhf(s);                       // pre-apply 0.1*tanh for epilogue
}

// ---------------- host ----------------
extern "C" void kernel_launch(void* const* d_in, const int* in_sizes, int n_in,
                              void* d_out, int out_size, void* d_ws, size_t ws_size,
                              hipStream_t stream)
{
  (void)in_sizes; (void)n_in; (void)out_size; (void)ws_size;
  const float* x_cell = (const float*)d_in[0];
  const float* x_emb  = (const float*)d_in[1];
  const float* z_h    = (const float*)d_in[2];
  const int*   ei     = (const int*)d_in[3];
  const float* gw[2]  = {(const float*)d_in[4],  (const float*)d_in[8]};
  const float* gas[2] = {(const float*)d_in[5],  (const float*)d_in[9]};
  const float* gad[2] = {(const float*)d_in[6],  (const float*)d_in[10]};
  const float* gbi[2] = {(const float*)d_in[7],  (const float*)d_in[11]};
  const float* norm1  = (const float*)d_in[12];
  const float* norm2  = (const float*)d_in[13];
  const float* norm3  = (const float*)d_in[14];
  const float* kw = (const float*)d_in[15]; const float* kb = (const float*)d_in[16];
  const float* qw = (const float*)d_in[17]; const float* qb = (const float*)d_in[18];
  const float* vw = (const float*)d_in[19]; const float* vb = (const float*)d_in[20];
  const float* relk = (const float*)d_in[21];
  const float* relv = (const float*)d_in[22];
  const float* relp = (const float*)d_in[23];
  const float* aw = (const float*)d_in[24]; const float* ab = (const float*)d_in[25];
  const float* skip = (const float*)d_in[26];
  const float* injw = (const float*)d_in[27]; const float* injb = (const float*)d_in[28];
  const float* fw1 = (const float*)d_in[29]; const float* fb1 = (const float*)d_in[30];
  const float* fw2 = (const float*)d_in[31]; const float* fb2 = (const float*)d_in[32];

  const long ND = (long)NN*DDIM;
  float* X    = (float*)d_ws;                    // x1 / x2 (f32)
  float* K    = X + ND;                          // 2x bf16 buffers
  bfraw* Xb   = (bfraw*)(K + ND);                // bf16 GEMM A; later HGT attn out
  bfraw* Hb   = Xb + ND;                         // bf16: h0 / kt0 / vt0
  float* Sbuf = (float*)(Hb + ND);               // GAT SS [T][N][8] | HGT E [3E][4]
  float* sA   = Sbuf + (long)NTYPE*NEDGE*4;      // spare
  float* sB   = sA + (long)NN*4;                 // spare
  float* WkE  = sB + (long)NN*4;
  float* bkE  = WkE + (long)NTYPE*DDIM*DDIM;
  float* WvE  = bkE + (long)NTYPE*DDIM;
  float* bvE  = WvE + (long)NTYPE*DDIM*DDIM;
  bfraw* Pswz = (bfraw*)(bvE + (long)NTYPE*DDIM);   // 2 layers x 4096 bf16
  bfraw* Wall = Pswz + (long)2*4096;                // 15 swizzled bf16 weights
  float* f1b  = (float*)(Wall + (long)15*16384);
  float* gbb  = f1b + (long)NGRAPH*256;
  int*   deg  = (int*)(gbb + (long)NGRAPH*256);  // 3N (reused as cnt)
  int*   rp   = deg + (long)NTYPE*NN;            // 3(N+1)
  int*   srcs = rp  + (long)NTYPE*(NN+1);        // 3E
  int*   csum = srcs + (long)NTYPE*NEDGE;        // 192

  bfraw* Kb0 = (bfraw*)K;                        // K as 2 bf16 buffers
  bfraw* Kb1 = Kb0 + ND;
  bfraw* qscr = (bfraw*)d_out;                   // d_out as q scratch (32 of 64 MB)

  const dim3 b256(256);
  float* NF = nullptr;
  bfraw* NB = nullptr; (void)sA; (void)sB;

  // ---------- CSR build ----------
  fill_k<<<256, b256, 0, stream>>>((float*)deg, 0.f, NTYPE*NN);
  hist_k<<<(NTYPE*NEDGE)/256, b256, 0, stream>>>(ei, deg);
  scan_a_k<<<dim3(64, NTYPE), b256, 0, stream>>>(deg, rp, csum);
  scan_b_k<<<NTYPE, 64, 0, stream>>>(csum);
  scan_c_k<<<dim3(64, NTYPE), b256, 0, stream>>>(rp, csum);
  fill_k<<<256, b256, 0, stream>>>((float*)deg, 0.f, NTYPE*NN);   // cnt
  scatter_k<<<(NTYPE*NEDGE)/256, b256, 0, stream>>>(ei, rp, deg, srcs);

  // ---------- weight prep ----------
  fold_k<<<(NTYPE*DDIM*DDIM)/256, b256, 0, stream>>>(kw, kb, relk, relp, WkE, bkE);
  fold_k<<<(NTYPE*DDIM*DDIM)/256, b256, 0, stream>>>(vw, vb, relv, NF, WvE, bvE);
  wswz_k<<<dim3(64, 15), b256, 0, stream>>>(
      gw[0], gw[0]+16384, gw[0]+32768,
      gw[1], gw[1]+16384, gw[1]+32768,
      qw, WkE, WvE, aw, injw, Wall);
  gatproj_k<<<16, b256, 0, stream>>>(gw[0], gas[0], gad[0], Pswz);
  gatproj_k<<<16, b256, 0, stream>>>(gw[1], gas[1], gad[1], Pswz + 4096);

  // ---------- FiLM (independent, run early) ----------
  film1_k<<<(NGRAPH*256)/256, b256, 0, stream>>>(z_h, fw1, fb1, f1b);
  film2_k<<<(NGRAPH*256)/256, b256, 0, stream>>>(f1b, fw2, fb2, gbb);

  // ---------- GAT layers ----------
  for (int layer=0; layer<2; layer++){
    gemm3_k<<<NN/128, b256, 0, stream>>>(
        Xb, (layer==0) ? x_cell : NF,
        Wall + (long)(layer*3+0)*16384, Wall + (long)(layer*3+1)*16384,
        Wall + (long)(layer*3+2)*16384,
        NF, NF, NF,
        Hb, Kb0, Kb1,
        Pswz + (long)layer*4096, Sbuf,
        NB, NF, NB);
    gat_fused_k<<<NN/8, b256, 0, stream>>>(
        rp, srcs, Hb, Kb0, Kb1, Sbuf, gbi[layer],
        (layer==0) ? x_cell : X, (layer==0) ? norm1 : norm2, X, Xb);
  }

  // ---------- HGT ----------
  // kt0->Hb, kt1->Kb0, kt2->Kb1, q->qscr (d_out scratch) — A read once
  gemm3_k<<<NN/128, b256, 0, stream>>>(
      Xb, NF,
      Wall + (long)7*16384, Wall + (long)8*16384, Wall + (long)9*16384,
      bkE, bkE + DDIM, bkE + 2*DDIM,
      Hb, Kb0, Kb1,
      NB, NF,
      Wall + (long)6*16384, qb, qscr);
  hgt_score3_k<<<NN/8, b256, 0, stream>>>(rp, srcs, qscr, Hb, Kb0, Kb1, Sbuf);
  // vt0..2 -> Hb, Kb0, Kb1 (kt dead), A read once
  gemm3_k<<<NN/128, b256, 0, stream>>>(
      Xb, NF,
      Wall + (long)10*16384, Wall + (long)11*16384, Wall + (long)12*16384,
      bvE, bvE + DDIM, bvE + 2*DDIM,
      Hb, Kb0, Kb1,
      NB, NF, NB, NF, NB);
  hgt_acc_fused_k<<<NN/8, b256, 0, stream>>>(rp, srcs, Sbuf, Hb, Kb0, Kb1, Xb);
  // fused: GEMM(attn@aw) + res3 + GEMM(x_emb@injw) + FiLM -> out (x3 never stored)
  gemm_r3film_k<<<NN/128, b256, 0, stream>>>(
      Xb, Wall + (long)13*16384, ab, X, norm3, skip,
      x_emb, Wall + (long)14*16384, injb, gbb, (float*)d_out);
}

// Round 6
// 848.866 us; speedup vs baseline: 1.0485x; 1.0246x over previous
//
#include <hip/hip_runtime.h>
#include <math.h>
#include <cstdint>

// ---------------- problem constants ----------------
#define NN     131072     // nodes
#define DDIM   128        // hidden dim
#define NHEAD  4
#define HDIM   32
#define NTYPE  3
#define NEDGE  262144     // edges per type (2^18)
#define NGRAPH 512
#define EPSV   1e-6f
#define SLOPEV 0.2f

typedef unsigned short bfraw;
typedef __attribute__((ext_vector_type(8))) short bf16x8;
typedef __attribute__((ext_vector_type(4))) float f32x4;

// ---------------- helpers ----------------
__device__ __forceinline__ float lrelu(float x){ return x >= 0.f ? x : SLOPEV*x; }
__device__ __forceinline__ float gelu_f(float x){ return 0.5f*x*(1.f+erff(x*0.70710678118654752f)); }
__device__ __forceinline__ bfraw f2bf(float f){
  unsigned int u = __float_as_uint(f);
  u += 0x7fffu + ((u >> 16) & 1u);          // RNE
  return (bfraw)(u >> 16);
}
__device__ __forceinline__ float4 ld_bf4(const bfraw* p){
  uint2 u = *reinterpret_cast<const uint2*>(p);
  float4 r;
  r.x = __uint_as_float(u.x << 16); r.y = __uint_as_float(u.x & 0xffff0000u);
  r.z = __uint_as_float(u.y << 16); r.w = __uint_as_float(u.y & 0xffff0000u);
  return r;
}
__device__ __forceinline__ void ld_bf8(const bfraw* p, float* o){
  uint4 v = *reinterpret_cast<const uint4*>(p);
  unsigned int w[4] = {v.x, v.y, v.z, v.w};
  #pragma unroll
  for (int i=0;i<4;i++){
    o[2*i]   = __uint_as_float(w[i] << 16);
    o[2*i+1] = __uint_as_float(w[i] & 0xffff0000u);
  }
}
__device__ __forceinline__ bf16x8 pack_bf8(const float* p){
  float4 u = *reinterpret_cast<const float4*>(p);
  float4 v = *reinterpret_cast<const float4*>(p+4);
  bf16x8 r;
  r[0]=(short)f2bf(u.x); r[1]=(short)f2bf(u.y); r[2]=(short)f2bf(u.z); r[3]=(short)f2bf(u.w);
  r[4]=(short)f2bf(v.x); r[5]=(short)f2bf(v.y); r[6]=(short)f2bf(v.z); r[7]=(short)f2bf(v.w);
  return r;
}

// ---------------- generic fill ----------------
__global__ void fill_k(float* __restrict__ p, float v, int n){
  int i = blockIdx.x*blockDim.x + threadIdx.x;
  int stride = gridDim.x*blockDim.x;
  for (; i < n; i += stride) p[i] = v;
}

// ---------------- CSR build (dst-sorted, per edge type) ----------------
__global__ void hist_k(const int* __restrict__ ei, int* __restrict__ deg){
  int idx = blockIdx.x*256 + threadIdx.x;          // < 3E/2
  int t = idx >> 17, e = (idx & 131071)*2;
  int2 d = *reinterpret_cast<const int2*>(ei + (long)t*2*NEDGE + NEDGE + e);
  atomicAdd(&deg[t*NN + d.x], 1);
  atomicAdd(&deg[t*NN + d.y], 1);
}

__global__ void scan_a_k(const int* __restrict__ deg, int* __restrict__ rp,
                         int* __restrict__ csum){
  __shared__ int sh[256];
  int t = blockIdx.y, chunk = blockIdx.x, tid = threadIdx.x;
  const int* dp = deg + (long)t*NN + chunk*2048 + tid*8;
  int v[8]; int s = 0;
  #pragma unroll
  for (int i=0;i<8;i++){ v[i] = dp[i]; s += v[i]; }
  sh[tid] = s; __syncthreads();
  for (int off=1; off<256; off<<=1){
    int x = (tid>=off) ? sh[tid-off] : 0;
    __syncthreads();
    sh[tid] += x;
    __syncthreads();
  }
  int run = sh[tid] - s;                            // exclusive prefix
  int* op = rp + (long)t*(NN+1) + chunk*2048 + tid*8;
  #pragma unroll
  for (int i=0;i<8;i++){ op[i] = run; run += v[i]; }
  if (tid == 255) csum[t*64 + chunk] = sh[255];
}

__global__ void scan_b_k(int* __restrict__ csum){
  __shared__ int sh[64];
  int t = blockIdx.x, tid = threadIdx.x;
  int s = csum[t*64 + tid];
  sh[tid] = s; __syncthreads();
  for (int off=1; off<64; off<<=1){
    int x = (tid>=off) ? sh[tid-off] : 0;
    __syncthreads();
    sh[tid] += x;
    __syncthreads();
  }
  csum[t*64 + tid] = sh[tid] - s;                   // exclusive
}

// finalize rp AND zero the cnt array (merged fill)
__global__ void scan_c_k(int* __restrict__ rp, const int* __restrict__ csum,
                         int* __restrict__ cnt){
  int t = blockIdx.y, chunk = blockIdx.x, tid = threadIdx.x;
  int add = csum[t*64 + chunk];
  int* op = rp + (long)t*(NN+1) + chunk*2048 + tid*8;
  int* cp = cnt + (long)t*NN + chunk*2048 + tid*8;
  #pragma unroll
  for (int i=0;i<8;i++){ op[i] += add; cp[i] = 0; }
  if (chunk == 63 && tid == 255) rp[(long)t*(NN+1) + NN] = NEDGE;
}

__global__ void scatter_k(const int* __restrict__ ei, const int* __restrict__ rp,
                          int* __restrict__ cnt, int* __restrict__ srcs){
  int idx = blockIdx.x*256 + threadIdx.x;          // < 3E/2
  int t = idx >> 17, e = (idx & 131071)*2;
  int2 s = *reinterpret_cast<const int2*>(ei + (long)t*2*NEDGE + e);
  int2 d = *reinterpret_cast<const int2*>(ei + (long)t*2*NEDGE + NEDGE + e);
  int p0 = rp[(long)t*(NN+1) + d.x] + atomicAdd(&cnt[t*NN + d.x], 1);
  srcs[(long)t*NEDGE + p0] = s.x;
  int p1 = rp[(long)t*(NN+1) + d.y] + atomicAdd(&cnt[t*NN + d.y], 1);
  srcs[(long)t*NEDGE + p1] = s.y;
}

// ---------------- ALL weight prep in one launch -------------------------------------
// y 0..5: GAT W; y 6: qw; y 7..9: kt fold (rel_k, relp/sqrt scale) + bkE;
// y 10..12: vt fold (rel_v) + bvE; y 13: aw; y 14: injw; y 15,16: gatproj layer 0/1.
__global__ void wswz_all_k(
    const float* g0a, const float* g0b, const float* g0c,
    const float* g1a, const float* g1b, const float* g1c,
    const float* qw, const float* aw, const float* injw,
    const float* kw, const float* kb, const float* relk, const float* relp,
    const float* vw, const float* vb, const float* relv,
    const float* gw0, const float* gas0, const float* gad0,
    const float* gw1, const float* gas1, const float* gad1,
    bfraw* __restrict__ Wall, bfraw* __restrict__ Pswz,
    float* __restrict__ bkE, float* __restrict__ bvE)
{
  int y = blockIdx.y;
  int i = blockIdx.x*256 + threadIdx.x;            // < 16384
  int j = i & 7, lane = (i>>3) & 63, kc = (i>>9) & 3, nt = i >> 11;
  int k = kc*32 + ((lane>>4)<<3) + j;
  int n = nt*16 + (lane & 15);
  if (y < 7 || y == 13 || y == 14){
    const float* src;
    switch(y){
      case 0: src = g0a; break;  case 1: src = g0b; break;  case 2: src = g0c; break;
      case 3: src = g1a; break;  case 4: src = g1b; break;  case 5: src = g1c; break;
      case 6: src = qw; break;   case 13: src = aw; break;  default: src = injw; break;
    }
    Wall[(long)y*16384 + i] = f2bf(src[k*DDIM + n]);
  } else if (y < 13){
    int isK = (y < 10);
    int t = isK ? (y-7) : (y-10);
    const float* w   = isK ? kw : vw;
    const float* b   = isK ? kb : vb;
    const float* rel = isK ? relk : relv;
    int h = n >> 5, e = n & 31;
    float fs = isK ? relp[t*NHEAD + h]*0.17677669529663687f : 1.f;   // 1/sqrt(32)
    const float* wrow = w + (long)k*DDIM + h*HDIM;
    const float* relm = rel + ((long)(t*NHEAD + h)*HDIM)*HDIM + e;
    float s = 0.f;
    #pragma unroll 8
    for (int dd=0; dd<HDIM; dd++) s += wrow[dd] * relm[dd*HDIM];
    Wall[(long)y*16384 + i] = f2bf(s*fs);
    if (k == 0){
      float sb = 0.f;
      #pragma unroll 8
      for (int dd=0; dd<HDIM; dd++) sb += b[h*HDIM+dd] * relm[dd*HDIM];
      (isK ? bkE : bvE)[t*DDIM + n] = sb*fs;
    }
  } else {                                          // y 15,16: gatproj
    if (blockIdx.x >= 16) return;                   // i < 4096, nt in {0,1}
    int layer = y - 15;
    const float* w   = layer ? gw1 : gw0;
    const float* as_ = layer ? gas1 : gas0;
    const float* ad_ = layer ? gad1 : gad0;
    float s = 0.f;
    if (n < 24){
      int t = n >> 3, sd = (n >> 2) & 1, hh = n & 3;
      const float* a  = (sd ? ad_ : as_) + ((long)t*NHEAD + hh)*HDIM;
      const float* wr = w + ((long)t*DDIM + k)*DDIM + hh*HDIM;
      #pragma unroll 8
      for (int dd=0; dd<HDIM; dd++) s += wr[dd]*a[dd];
    }
    Pswz[(long)layer*4096 + i] = f2bf(s);
  }
}

// ---------------- MFMA GEMM building blocks -----------------------------------------
__device__ __forceinline__ void load_afrags_bf16(const bfraw* __restrict__ A,
    long blockRow, int tid, bf16x8 a0[4], bf16x8 a1[4])
{
  const int w = tid >> 6, lane = tid & 63;
  const long rowA = blockRow + w*32 + (lane & 15);
  const bfraw* A0 = A + rowA*DDIM + ((lane>>4)<<3);
  #pragma unroll
  for (int kc=0;kc<4;kc++){
    a0[kc] = *reinterpret_cast<const bf16x8*>(A0 + kc*32);
    a1[kc] = *reinterpret_cast<const bf16x8*>(A0 + 16*DDIM + kc*32);
  }
}

__device__ __forceinline__ void load_afrags_f32(const float* __restrict__ A,
    long blockRow, int tid, bf16x8 a0[4], bf16x8 a1[4])
{
  const int w = tid >> 6, lane = tid & 63;
  const long rowA = blockRow + w*32 + (lane & 15);
  const float* A0 = A + rowA*DDIM + ((lane>>4)<<3);
  #pragma unroll
  for (int kc=0;kc<4;kc++){
    a0[kc] = pack_bf8(A0 + kc*32);
    a1[kc] = pack_bf8(A0 + 16*DDIM + kc*32);
  }
}

__device__ __forceinline__ void mfma_128(const bfraw* Wl, int lane,
    bf16x8 a0[4], bf16x8 a1[4], f32x4 acc0[8], f32x4 acc1[8])
{
  const f32x4 zz = {0.f,0.f,0.f,0.f};
  #pragma unroll
  for (int nt=0;nt<8;nt++){ acc0[nt]=zz; acc1[nt]=zz; }
  #pragma unroll
  for (int nt=0;nt<8;nt++){
    #pragma unroll
    for (int kc=0;kc<4;kc++){
      bf16x8 b = *reinterpret_cast<const bf16x8*>(Wl + ((nt*4+kc)*64 + lane)*8);
      acc0[nt] = __builtin_amdgcn_mfma_f32_16x16x32_bf16(a0[kc], b, acc0[nt], 0, 0, 0);
      acc1[nt] = __builtin_amdgcn_mfma_f32_16x16x32_bf16(a1[kc], b, acc1[nt], 0, 0, 0);
    }
  }
}

__device__ __forceinline__ void gemm_store_bf16(f32x4 acc0[8], f32x4 acc1[8],
    const float* bias, bfraw* __restrict__ Cb, long blockRow, int tid)
{
  const int w = tid>>6, lane = tid&63, q = lane>>4;
  #pragma unroll
  for (int g=0; g<2; g++){
    #pragma unroll
    for (int nt=0;nt<8;nt++){
      int col = nt*16 + (lane & 15);
      float bv = bias ? bias[col] : 0.f;
      #pragma unroll
      for (int r=0;r<4;r++){
        long row = blockRow + w*32 + g*16 + q*4 + r;
        float v = (g ? acc1[nt][r] : acc0[nt][r]) + bv;
        Cb[row*DDIM + col] = f2bf(v);
      }
    }
  }
}

// ---- up to 4 GEMMs sharing one A-read (+ optional 24-col score GEMM tail) ----------
__global__ __launch_bounds__(256) void gemm3_k(
    const bfraw* __restrict__ Ab, const float* __restrict__ Af,
    const bfraw* __restrict__ W0, const bfraw* __restrict__ W1,
    const bfraw* __restrict__ W2,
    const float* __restrict__ b0, const float* __restrict__ b1,
    const float* __restrict__ b2,
    bfraw* __restrict__ O0, bfraw* __restrict__ O1, bfraw* __restrict__ O2,
    const bfraw* __restrict__ Psw, float* __restrict__ SS,
    const bfraw* __restrict__ W3, const float* __restrict__ b3,
    bfraw* __restrict__ O3)
{
  __shared__ bfraw Wl[16384];
  const int tid = threadIdx.x;
  const long blockRow = (long)blockIdx.x * 128;
  const int w = tid >> 6, lane = tid & 63;
  bf16x8 a0[4], a1[4];
  if (Af) load_afrags_f32(Af, blockRow, tid, a0, a1);
  else    load_afrags_bf16(Ab, blockRow, tid, a0, a1);
  const bfraw* Ws[3] = {W0, W1, W2};
  const float* bs[3] = {b0, b1, b2};
  bfraw* Os[3] = {O0, O1, O2};
  #pragma unroll
  for (int t=0;t<3;t++){
    __syncthreads();                                 // prev readers done
    #pragma unroll
    for (int i=0;i<8;i++)
      *reinterpret_cast<uint4*>(Wl + (i*256+tid)*8) =
          *reinterpret_cast<const uint4*>(Ws[t] + (i*256+tid)*8);
    __syncthreads();
    f32x4 acc0[8], acc1[8];
    mfma_128(Wl, lane, a0, a1, acc0, acc1);
    gemm_store_bf16(acc0, acc1, bs[t], Os[t], blockRow, tid);
  }
  if (W3){
    __syncthreads();
    #pragma unroll
    for (int i=0;i<8;i++)
      *reinterpret_cast<uint4*>(Wl + (i*256+tid)*8) =
          *reinterpret_cast<const uint4*>(W3 + (i*256+tid)*8);
    __syncthreads();
    f32x4 acc0[8], acc1[8];
    mfma_128(Wl, lane, a0, a1, acc0, acc1);
    gemm_store_bf16(acc0, acc1, b3, O3, blockRow, tid);
  }
  if (Psw){
    __syncthreads();
    #pragma unroll
    for (int i=0;i<2;i++)
      *reinterpret_cast<uint4*>(Wl + (i*256+tid)*8) =
          *reinterpret_cast<const uint4*>(Psw + (i*256+tid)*8);
    __syncthreads();
    const f32x4 zz = {0.f,0.f,0.f,0.f};
    f32x4 acc0[2], acc1[2];
    #pragma unroll
    for (int nt=0;nt<2;nt++){ acc0[nt]=zz; acc1[nt]=zz; }
    #pragma unroll
    for (int nt=0;nt<2;nt++){
      #pragma unroll
      for (int kc=0;kc<4;kc++){
        bf16x8 b = *reinterpret_cast<const bf16x8*>(Wl + ((nt*4+kc)*64 + lane)*8);
        acc0[nt] = __builtin_amdgcn_mfma_f32_16x16x32_bf16(a0[kc], b, acc0[nt], 0, 0, 0);
        acc1[nt] = __builtin_amdgcn_mfma_f32_16x16x32_bf16(a1[kc], b, acc1[nt], 0, 0, 0);
      }
    }
    const int q = lane >> 4;
    #pragma unroll
    for (int g=0; g<2; g++){
      #pragma unroll
      for (int nt=0;nt<2;nt++){
        int col = nt*16 + (lane & 15);
        if (col < 24){
          int tt = col >> 3, c = col & 7;           // SS layout [T][NN][8]
          #pragma unroll
          for (int r=0;r<4;r++){
            long row = blockRow + w*32 + g*16 + q*4 + r;
            SS[(((long)tt*NN + row)<<3) + c] = (g ? acc1[nt][r] : acc0[nt][r]);
          }
        }
      }
    }
  }
}

// ---- fused: GEMM(attn@aw) + res3 + GEMM(x_emb@injw) + FiLM -> out ------------------
__global__ __launch_bounds__(256) void gemm_r3film_k(
    const bfraw* __restrict__ Aattn, const bfraw* __restrict__ Waw,
    const float* __restrict__ ab, const float* __restrict__ X,
    const float* __restrict__ norm, const float* __restrict__ skip,
    const float* __restrict__ xemb, const bfraw* __restrict__ Winj,
    const float* __restrict__ injb, const float* __restrict__ gbt,
    float* __restrict__ out)
{
  __shared__ bfraw Wl[16384];
  const int tid = threadIdx.x;
  const long blockRow = (long)blockIdx.x * 128;
  // GEMM1: attn-out @ aw
  #pragma unroll
  for (int i=0;i<8;i++)
    *reinterpret_cast<uint4*>(Wl + (i*256+tid)*8) =
        *reinterpret_cast<const uint4*>(Waw + (i*256+tid)*8);
  __syncthreads();
  bf16x8 a0[4], a1[4];
  load_afrags_bf16(Aattn, blockRow, tid, a0, a1);
  f32x4 accA0[8], accA1[8];
  mfma_128(Wl, tid & 63, a0, a1, accA0, accA1);
  __syncthreads();
  // GEMM2: x_emb(f32) @ injw
  #pragma unroll
  for (int i=0;i<8;i++)
    *reinterpret_cast<uint4*>(Wl + (i*256+tid)*8) =
        *reinterpret_cast<const uint4*>(Winj + (i*256+tid)*8);
  __syncthreads();
  load_afrags_f32(xemb, blockRow, tid, a0, a1);
  f32x4 accB0[8], accB1[8];
  mfma_128(Wl, tid & 63, a0, a1, accB0, accB1);
  // epilogue
  const int w = tid>>6, lane = tid&63, q = lane>>4;
  const float gsk = 1.f/(1.f + __expf(-skip[0]));
  #pragma unroll
  for (int g=0; g<2; g++){
    #pragma unroll
    for (int r=0;r<4;r++){
      long row = blockRow + w*32 + g*16 + q*4 + r;
      float vv[8], xx[8];
      float sq = 0.f;
      #pragma unroll
      for (int nt=0;nt<8;nt++){
        int col = nt*16 + (lane & 15);
        float oA = (g ? accA1[nt][r] : accA0[nt][r]) + ab[col];
        float xo = X[row*DDIM + col];
        float v  = gsk*oA + (1.f-gsk)*xo;
        vv[nt] = v; xx[nt] = xo; sq += v*v;
      }
      sq += __shfl_xor(sq, 1, 64);
      sq += __shfl_xor(sq, 2, 64);
      sq += __shfl_xor(sq, 4, 64);
      sq += __shfl_xor(sq, 8, 64);
      float rr = rsqrtf(sq*(1.f/DDIM) + EPSV);
      long gi = row >> 8;                             // 256 nodes per graph
      #pragma unroll
      for (int nt=0;nt<8;nt++){
        int col = nt*16 + (lane & 15);
        float x3 = lrelu(xx[nt] + norm[col]*vv[nt]*rr);
        float vB = (g ? accB1[nt][r] : accB0[nt][r]) + injb[col] + x3;
        out[row*DDIM + col] = (1.f + gbt[gi*256 + col])*vB + gbt[gi*256 + 128 + col];
      }
    }
  }
}

// ---------------- fused GAT: 16 lanes/node, ld_bf8 gathers, 2-wide dual chains ------
// SS layout: [T][NN][8], cols 0..3 = ss per head, 4..7 = ds per head.
__global__ __launch_bounds__(256) void gat_fused_k(
    const int* __restrict__ rp, const int* __restrict__ srcs,
    const bfraw* __restrict__ H0, const bfraw* __restrict__ H1,
    const bfraw* __restrict__ H2, const float* __restrict__ SS,
    const float* __restrict__ gatb, const float* __restrict__ xold,
    const float* __restrict__ norm, float* __restrict__ X, bfraw* __restrict__ Xb)
{
  int node = blockIdx.x*16 + (threadIdx.x >> 4);
  int l = threadIdx.x & 15;                  // lane covers features l*8 .. l*8+7
  int hd = l >> 2;                           // head
  const bfraw* Hs[3] = {H0, H1, H2};
  float dsv[3], ssl[3]; int beg[3], end[3];
  #pragma unroll
  for (int t=0; t<3; t++){
    const float* St = SS + ((long)t*NN)*8;
    dsv[t] = St[(long)node*8 + 4 + hd];
    ssl[t] = St[(long)node*8 + hd];
    beg[t] = rp[t*(NN+1) + node];
    end[t] = rp[t*(NN+1) + node + 1];
  }
  float tx[8];
  #pragma unroll
  for (int j=0;j<8;j++) tx[j] = 0.f;
  #pragma unroll
  for (int t=0; t<3; t++){
    const bfraw* Ht = Hs[t];
    const float* St = SS + ((long)t*NN)*8;
    const int* sp = srcs + (long)t*NEDGE;
    const float d = dsv[t];
    float hs[8];
    ld_bf8(Ht + (long)node*DDIM + l*8, hs);  // self row
    float e = __expf(lrelu(ssl[t] + d));
    float lA = e, lB = 0.f;
    float aA[8], aB[8];
    #pragma unroll
    for (int j=0;j<8;j++){ aA[j] = e*hs[j]; aB[j] = 0.f; }
    int p = beg[t];
    for (; p+1 < end[t]; p += 2){            // 2-wide dual chains
      int s0 = sp[p], s1 = sp[p+1];
      float v0 = St[(long)s0*8 + hd];
      float v1 = St[(long)s1*8 + hd];
      float h0[8], h1[8];
      ld_bf8(Ht + (long)s0*DDIM + l*8, h0);
      ld_bf8(Ht + (long)s1*DDIM + l*8, h1);
      float e0 = __expf(lrelu(v0 + d));
      float e1 = __expf(lrelu(v1 + d));
      lA += e0; lB += e1;
      #pragma unroll
      for (int j=0;j<8;j++){ aA[j] += e0*h0[j]; aB[j] += e1*h1[j]; }
    }
    if (p < end[t]){
      int s0 = sp[p];
      float e0 = __expf(lrelu(St[(long)s0*8 + hd] + d));
      float h0[8];
      ld_bf8(Ht + (long)s0*DDIM + l*8, h0);
      lA += e0;
      #pragma unroll
      for (int j=0;j<8;j++) aA[j] += e0*h0[j];
    }
    float inv = 1.f/(lA + lB);
    #pragma unroll
    for (int j=0;j<8;j++) tx[j] += (aA[j] + aB[j])*inv;
  }
  int f = l*8;
  #pragma unroll
  for (int j=0;j<8;j++)
    tx[j] += gatb[f+j] + gatb[DDIM+f+j] + gatb[2*DDIM+f+j];
  float sq = 0.f;
  #pragma unroll
  for (int j=0;j<8;j++) sq += tx[j]*tx[j];
  sq += __shfl_xor(sq, 1, 64);
  sq += __shfl_xor(sq, 2, 64);
  sq += __shfl_xor(sq, 4, 64);
  sq += __shfl_xor(sq, 8, 64);
  float r = rsqrtf(sq*(1.f/DDIM) + EPSV);
  float4 xa = *reinterpret_cast<const float4*>(xold + (long)node*DDIM + f);
  float4 xb = *reinterpret_cast<const float4*>(xold + (long)node*DDIM + f + 4);
  float o[8];
  o[0] = lrelu(xa.x + norm[f+0]*tx[0]*r);
  o[1] = lrelu(xa.y + norm[f+1]*tx[1]*r);
  o[2] = lrelu(xa.z + norm[f+2]*tx[2]*r);
  o[3] = lrelu(xa.w + norm[f+3]*tx[3]*r);
  o[4] = lrelu(xb.x + norm[f+4]*tx[4]*r);
  o[5] = lrelu(xb.y + norm[f+5]*tx[5]*r);
  o[6] = lrelu(xb.z + norm[f+6]*tx[6]*r);
  o[7] = lrelu(xb.w + norm[f+7]*tx[7]*r);
  *reinterpret_cast<float4*>(X + (long)node*DDIM + f)     = make_float4(o[0],o[1],o[2],o[3]);
  *reinterpret_cast<float4*>(X + (long)node*DDIM + f + 4) = make_float4(o[4],o[5],o[6],o[7]);
  uint4 u;
  u.x = ((unsigned int)f2bf(o[1]) << 16) | f2bf(o[0]);
  u.y = ((unsigned int)f2bf(o[3]) << 16) | f2bf(o[2]);
  u.z = ((unsigned int)f2bf(o[5]) << 16) | f2bf(o[4]);
  u.w = ((unsigned int)f2bf(o[7]) << 16) | f2bf(o[6]);
  *reinterpret_cast<uint4*>(Xb + (long)node*DDIM + f) = u;
}

// ---------------- HGT scores: 3 types sequential, q read once, 2-wide ---------------
__global__ __launch_bounds__(256) void hgt_score3_k(
    const int* __restrict__ rp, const int* __restrict__ srcs,
    const bfraw* __restrict__ qb, const bfraw* __restrict__ kt0,
    const bfraw* __restrict__ kt1, const bfraw* __restrict__ kt2,
    float* __restrict__ E)
{
  int node = blockIdx.x*8 + (threadIdx.x >> 5);
  int l = threadIdx.x & 31;
  int hd = l >> 3, sub = l & 7;
  float4 qv = ld_bf4(qb + (long)node*DDIM + l*4);
  const bfraw* kts[3] = {kt0, kt1, kt2};
  #pragma unroll
  for (int t=0; t<3; t++){
    const bfraw* kt = kts[t];
    const int* sp = srcs + (long)t*NEDGE;
    float* Et = E + (long)t*NEDGE*4;
    int beg = rp[t*(NN+1) + node], end = rp[t*(NN+1) + node + 1];
    int p = beg;
    for (; p+1 < end; p += 2){
      int s0 = sp[p], s1 = sp[p+1];
      float4 k0 = ld_bf4(kt + (long)s0*DDIM + l*4);
      float4 k1 = ld_bf4(kt + (long)s1*DDIM + l*4);
      float d0 = qv.x*k0.x + qv.y*k0.y + qv.z*k0.z + qv.w*k0.w;
      float d1 = qv.x*k1.x + qv.y*k1.y + qv.z*k1.z + qv.w*k1.w;
      d0 += __shfl_xor(d0, 1, 64);  d1 += __shfl_xor(d1, 1, 64);
      d0 += __shfl_xor(d0, 2, 64);  d1 += __shfl_xor(d1, 2, 64);
      d0 += __shfl_xor(d0, 4, 64);  d1 += __shfl_xor(d1, 4, 64);
      if (sub == 0){
        Et[(long)p*4 + hd]     = __expf(d0);
        Et[(long)(p+1)*4 + hd] = __expf(d1);
      }
    }
    if (p < end){
      int s0 = sp[p];
      float4 k0 = ld_bf4(kt + (long)s0*DDIM + l*4);
      float d0 = qv.x*k0.x + qv.y*k0.y + qv.z*k0.z + qv.w*k0.w;
      d0 += __shfl_xor(d0, 1, 64);
      d0 += __shfl_xor(d0, 2, 64);
      d0 += __shfl_xor(d0, 4, 64);
      if (sub == 0) Et[(long)p*4 + hd] = __expf(d0);
    }
  }
}

// ---------------- HGT fused acc: 3 types sequential, dual chains, gelu -> bf16 ------
__global__ __launch_bounds__(256) void hgt_acc_fused_k(
    const int* __restrict__ rp, const int* __restrict__ srcs,
    const float* __restrict__ E, const bfraw* __restrict__ V0,
    const bfraw* __restrict__ V1, const bfraw* __restrict__ V2,
    bfraw* __restrict__ out)
{
  int node = blockIdx.x*8 + (threadIdx.x >> 5);
  int l = threadIdx.x & 31;
  int hd = l >> 3;
  float axA=0.f, ayA=0.f, azA=0.f, awA=0.f, lsA=0.f;
  float axB=0.f, ayB=0.f, azB=0.f, awB=0.f, lsB=0.f;
  const bfraw* Vs[3] = {V0, V1, V2};
  #pragma unroll
  for (int t=0; t<3; t++){
    const bfraw* Vt = Vs[t];
    const float* Ep = E + (long)t*NEDGE*4;
    const int* sp = srcs + (long)t*NEDGE;
    int beg = rp[t*(NN+1) + node], end = rp[t*(NN+1) + node + 1];
    int p = beg;
    for (; p+1 < end; p += 2){
      int s0 = sp[p], s1 = sp[p+1];
      float e0 = Ep[(long)p*4 + hd];
      float e1 = Ep[(long)(p+1)*4 + hd];
      float4 v0 = ld_bf4(Vt + (long)s0*DDIM + l*4);
      float4 v1 = ld_bf4(Vt + (long)s1*DDIM + l*4);
      axA += e0*v0.x; ayA += e0*v0.y; azA += e0*v0.z; awA += e0*v0.w; lsA += e0;
      axB += e1*v1.x; ayB += e1*v1.y; azB += e1*v1.z; awB += e1*v1.w; lsB += e1;
    }
    if (p < end){
      int s0 = sp[p];
      float e0 = Ep[(long)p*4 + hd];
      float4 v0 = ld_bf4(Vt + (long)s0*DDIM + l*4);
      axA += e0*v0.x; ayA += e0*v0.y; azA += e0*v0.z; awA += e0*v0.w; lsA += e0;
    }
  }
  float lsum = lsA + lsB;
  float inv = (lsum > 0.f) ? 1.f/lsum : 0.f;
  float o0 = gelu_f((axA+axB)*inv), o1 = gelu_f((ayA+ayB)*inv);
  float o2 = gelu_f((azA+azB)*inv), o3 = gelu_f((awA+awB)*inv);
  unsigned int lo = ((unsigned int)f2bf(o1) << 16) | f2bf(o0);
  unsigned int hi = ((unsigned int)f2bf(o3) << 16) | f2bf(o2);
  *reinterpret_cast<uint2*>(out + (long)node*DDIM + l*4) = make_uint2(lo, hi);
}

// ---------------- FiLM ----------------
__global__ void film1_k(const float* __restrict__ z, const float* __restrict__ w1,
                        const float* __restrict__ b1, float* __restrict__ f1)
{
  int idx = blockIdx.x*256 + threadIdx.x;
  if (idx >= NGRAPH*256) return;
  int j = idx & 255, b = idx >> 8;
  const float* zr = z + (long)b*DDIM;
  float s = b1[j];
  for (int k=0;k<DDIM;k++) s += zr[k] * w1[(long)k*256 + j];
  f1[idx] = gelu_f(s);
}

__global__ void film2_k(const float* __restrict__ f1, const float* __restrict__ w2,
                        const float* __restrict__ b2, float* __restrict__ gb)
{
  int idx = blockIdx.x*256 + threadIdx.x;
  if (idx >= NGRAPH*256) return;
  int j = idx & 255, b = idx >> 8;
  const float* fr = f1 + (long)b*256;
  float s = b2[j];
  for (int k=0;k<256;k++) s += fr[k] * w2[(long)k*256 + j];
  gb[idx] = 0.1f*tanhf(s);                       // pre-apply 0.1*tanh for epilogue
}

// ---------------- host ----------------
extern "C" void kernel_launch(void* const* d_in, const int* in_sizes, int n_in,
                              void* d_out, int out_size, void* d_ws, size_t ws_size,
                              hipStream_t stream)
{
  (void)in_sizes; (void)n_in; (void)out_size; (void)ws_size;
  const float* x_cell = (const float*)d_in[0];
  const float* x_emb  = (const float*)d_in[1];
  const float* z_h    = (const float*)d_in[2];
  const int*   ei     = (const int*)d_in[3];
  const float* gw[2]  = {(const float*)d_in[4],  (const float*)d_in[8]};
  const float* gas[2] = {(const float*)d_in[5],  (const float*)d_in[9]};
  const float* gad[2] = {(const float*)d_in[6],  (const float*)d_in[10]};
  const float* gbi[2] = {(const float*)d_in[7],  (const float*)d_in[11]};
  const float* norm1  = (const float*)d_in[12];
  const float* norm2  = (const float*)d_in[13];
  const float* norm3  = (const float*)d_in[14];
  const float* kw = (const float*)d_in[15]; const float* kb = (const float*)d_in[16];
  const float* qw = (const float*)d_in[17]; const float* qb = (const float*)d_in[18];
  const float* vw = (const float*)d_in[19]; const float* vb = (const float*)d_in[20];
  const float* relk = (const float*)d_in[21];
  const float* relv = (const float*)d_in[22];
  const float* relp = (const float*)d_in[23];
  const float* aw = (const float*)d_in[24]; const float* ab = (const float*)d_in[25];
  const float* skip = (const float*)d_in[26];
  const float* injw = (const float*)d_in[27]; const float* injb = (const float*)d_in[28];
  const float* fw1 = (const float*)d_in[29]; const float* fb1 = (const float*)d_in[30];
  const float* fw2 = (const float*)d_in[31]; const float* fb2 = (const float*)d_in[32];

  const long ND = (long)NN*DDIM;
  float* X    = (float*)d_ws;                    // x1 / x2 (f32)
  float* K    = X + ND;                          // 2x bf16 buffers
  bfraw* Xb   = (bfraw*)(K + ND);                // bf16 GEMM A; later HGT attn out
  bfraw* Hb   = Xb + ND;                         // bf16: h0 / kt0 / vt0
  float* Sbuf = (float*)(Hb + ND);               // GAT SS [T][N][8] | HGT E [3E][4]
  float* sA   = Sbuf + (long)NTYPE*NEDGE*4;      // spare
  float* sB   = sA + (long)NN*4;                 // spare
  float* WkE  = sB + (long)NN*4;                 // (unused staging, kept for layout)
  float* bkE  = WkE + (long)NTYPE*DDIM*DDIM;
  float* WvE  = bkE + (long)NTYPE*DDIM;
  float* bvE  = WvE + (long)NTYPE*DDIM*DDIM;
  bfraw* Pswz = (bfraw*)(bvE + (long)NTYPE*DDIM);   // 2 layers x 4096 bf16
  bfraw* Wall = Pswz + (long)2*4096;                // 15 swizzled bf16 weights
  float* f1b  = (float*)(Wall + (long)15*16384);
  float* gbb  = f1b + (long)NGRAPH*256;
  int*   deg  = (int*)(gbb + (long)NGRAPH*256);  // 3N (reused as cnt)
  int*   rp   = deg + (long)NTYPE*NN;            // 3(N+1)
  int*   srcs = rp  + (long)NTYPE*(NN+1);        // 3E
  int*   csum = srcs + (long)NTYPE*NEDGE;        // 192

  bfraw* Kb0 = (bfraw*)K;                        // K as 2 bf16 buffers
  bfraw* Kb1 = Kb0 + ND;
  bfraw* qscr = (bfraw*)d_out;                   // d_out as q scratch (32 of 64 MB)

  const dim3 b256(256);
  float* NF = nullptr;
  bfraw* NB = nullptr; (void)sA; (void)sB; (void)WkE; (void)WvE;

  // ---------- CSR build ----------
  fill_k<<<256, b256, 0, stream>>>((float*)deg, 0.f, NTYPE*NN);
  hist_k<<<(NTYPE*NEDGE/2)/256, b256, 0, stream>>>(ei, deg);
  scan_a_k<<<dim3(64, NTYPE), b256, 0, stream>>>(deg, rp, csum);
  scan_b_k<<<NTYPE, 64, 0, stream>>>(csum);
  scan_c_k<<<dim3(64, NTYPE), b256, 0, stream>>>(rp, csum, deg);   // also zeroes cnt
  scatter_k<<<(NTYPE*NEDGE/2)/256, b256, 0, stream>>>(ei, rp, deg, srcs);

  // ---------- ALL weight prep in one launch ----------
  wswz_all_k<<<dim3(64, 17), b256, 0, stream>>>(
      gw[0], gw[0]+16384, gw[0]+32768,
      gw[1], gw[1]+16384, gw[1]+32768,
      qw, aw, injw,
      kw, kb, relk, relp, vw, vb, relv,
      gw[0], gas[0], gad[0], gw[1], gas[1], gad[1],
      Wall, Pswz, bkE, bvE);

  // ---------- FiLM (independent, run early) ----------
  film1_k<<<(NGRAPH*256)/256, b256, 0, stream>>>(z_h, fw1, fb1, f1b);
  film2_k<<<(NGRAPH*256)/256, b256, 0, stream>>>(f1b, fw2, fb2, gbb);

  // ---------- GAT layers ----------
  for (int layer=0; layer<2; layer++){
    gemm3_k<<<NN/128, b256, 0, stream>>>(
        Xb, (layer==0) ? x_cell : NF,
        Wall + (long)(layer*3+0)*16384, Wall + (long)(layer*3+1)*16384,
        Wall + (long)(layer*3+2)*16384,
        NF, NF, NF,
        Hb, Kb0, Kb1,
        Pswz + (long)layer*4096, Sbuf,
        NB, NF, NB);
    gat_fused_k<<<NN/16, b256, 0, stream>>>(
        rp, srcs, Hb, Kb0, Kb1, Sbuf, gbi[layer],
        (layer==0) ? x_cell : X, (layer==0) ? norm1 : norm2, X, Xb);
  }

  // ---------- HGT ----------
  // kt0->Hb, kt1->Kb0, kt2->Kb1, q->qscr (d_out scratch) — A read once
  gemm3_k<<<NN/128, b256, 0, stream>>>(
      Xb, NF,
      Wall + (long)7*16384, Wall + (long)8*16384, Wall + (long)9*16384,
      bkE, bkE + DDIM, bkE + 2*DDIM,
      Hb, Kb0, Kb1,
      NB, NF,
      Wall + (long)6*16384, qb, qscr);
  hgt_score3_k<<<NN/8, b256, 0, stream>>>(rp, srcs, qscr, Hb, Kb0, Kb1, Sbuf);
  // vt0..2 -> Hb, Kb0, Kb1 (kt dead), A read once
  gemm3_k<<<NN/128, b256, 0, stream>>>(
      Xb, NF,
      Wall + (long)10*16384, Wall + (long)11*16384, Wall + (long)12*16384,
      bvE, bvE + DDIM, bvE + 2*DDIM,
      Hb, Kb0, Kb1,
      NB, NF, NB, NF, NB);
  hgt_acc_fused_k<<<NN/8, b256, 0, stream>>>(rp, srcs, Sbuf, Hb, Kb0, Kb1, Xb);
  // fused: GEMM(attn@aw) + res3 + GEMM(x_emb@injw) + FiLM -> out (x3 never stored)
  gemm_r3film_k<<<NN/128, b256, 0, stream>>>(
      Xb, Wall + (long)13*16384, ab, X, norm3, skip,
      x_emb, Wall + (long)14*16384, injb, gbb, (float*)d_out);
}